// Round 15
// baseline (176.340 us; speedup 1.0000x reference)
//
#include <hip/hip_runtime.h>
#include <math.h>

constexpr int CC    = 64;          // channels
constexpr int GG    = 8;           // window size
constexpr int H0    = 256;
constexpr int W0c   = 256;
constexpr int BB    = 2;
constexpr int LL    = H0 * W0c;                     // 65536
constexpr int NWIN  = BB * (H0 / GG) * (W0c / GG);  // 2048
constexpr int HIDN  = 256;                          // MLP hidden
constexpr int NBIA  = 31 * 15;                      // 465 relative-pos entries
constexpr long long MODSZ = (long long)BB * LL * CC; // 8388608 floats per modality

constexpr float INV_LN2 = 1.4426950408889634f;

// ws byte offsets
constexpr int WS_PTAB  = 0;        // 465*4 f32
constexpr int WS_BIAS  = 8192;     // [4][128][128] f32 = 256 KB (pre-scaled by 1/ln2)
constexpr int WS_WQKV  = 270336;   // 24 slots * 512 bf16 = 24 KB (frag image)
constexpr int WS_WPROJ = 294912;   // 8 slots * 512 bf16 = 8 KB
constexpr int WS_MLPW  = 303104;   // 4 images * 16384 bf16 = 128 KB (A-frag images)

using f32x4  = __attribute__((ext_vector_type(4))) float;
using bf16x8 = __attribute__((ext_vector_type(8))) short;
using bf16x4 = __attribute__((ext_vector_type(4))) short;

static __device__ __forceinline__ short to_bf16(float f) {   // RNE (prep kernels)
  unsigned u = __float_as_uint(f);
  unsigned r = (u + 0x7FFFu + ((u >> 16) & 1u)) >> 16;
  return (short)r;
}
// hot-path packing: round-half-up, pair-packed in pure C (no asm — round-5 lesson)
static __device__ __forceinline__ bf16x4 mk4_bf16(float a, float b, float c, float d) {
  unsigned p0 = ((__float_as_uint(a) + 0x8000u) >> 16) | ((__float_as_uint(b) + 0x8000u) & 0xFFFF0000u);
  unsigned p1 = ((__float_as_uint(c) + 0x8000u) >> 16) | ((__float_as_uint(d) + 0x8000u) & 0xFFFF0000u);
  bf16x4 r;
  r[0] = (short)(p0 & 0xFFFFu); r[1] = (short)(p0 >> 16);
  r[2] = (short)(p1 & 0xFFFFu); r[3] = (short)(p1 >> 16);
  return r;
}
static __device__ __forceinline__ float gelu_tanh(float u) {
  float u2 = u * u;
  float t  = fmaf(0.044715f, u2, 1.0f);
  float z  = u * t * 1.5957691216057308f;
  float e  = __expf(-z);
  return u / (1.0f + e);
}

// ---------------------------------------------------------------------------
// Kernel P: dynamic position bias table (465 x 4) via tiny MLP
// ---------------------------------------------------------------------------
static __device__ __forceinline__ void ln4_relu(float* p, const float* g, const float* b) {
  float mu = 0.25f * (p[0] + p[1] + p[2] + p[3]);
  float d0 = p[0] - mu, d1 = p[1] - mu, d2 = p[2] - mu, d3 = p[3] - mu;
  float var = 0.25f * (d0 * d0 + d1 * d1 + d2 * d2 + d3 * d3);
  float rs = rsqrtf(var + 1e-5f);
  p[0] = fmaxf(d0 * rs * g[0] + b[0], 0.0f);
  p[1] = fmaxf(d1 * rs * g[1] + b[1], 0.0f);
  p[2] = fmaxf(d2 * rs * g[2] + b[2], 0.0f);
  p[3] = fmaxf(d3 * rs * g[3] + b[3], 0.0f);
}
static __device__ __forceinline__ void mm4(const float* a, const float* w, const float* b, float* o) {
  #pragma unroll
  for (int j = 0; j < 4; ++j) {
    float s = b[j];
    #pragma unroll
    for (int i = 0; i < 4; ++i) s += a[i] * w[i * 4 + j];
    o[j] = s;
  }
}

__global__ void pbias_kernel(const float* __restrict__ pp_w, const float* __restrict__ pp_b,
                             const float* __restrict__ ln1g, const float* __restrict__ ln1b,
                             const float* __restrict__ l1w,  const float* __restrict__ l1b,
                             const float* __restrict__ ln2g, const float* __restrict__ ln2b,
                             const float* __restrict__ l2w,  const float* __restrict__ l2b,
                             const float* __restrict__ ln3g, const float* __restrict__ ln3b,
                             const float* __restrict__ l3w,  const float* __restrict__ l3b,
                             float* __restrict__ p_table) {
  int r = blockIdx.x * blockDim.x + threadIdx.x;
  if (r >= NBIA) return;
  float bh = (float)(r / 15 - 15);
  float bw = (float)(r % 15 - 7);
  float a[4], t[4];
  #pragma unroll
  for (int j = 0; j < 4; ++j) a[j] = bh * pp_w[j] + bw * pp_w[4 + j] + pp_b[j];
  ln4_relu(a, ln1g, ln1b);
  mm4(a, l1w, l1b, t);
  ln4_relu(t, ln2g, ln2b);
  mm4(t, l2w, l2b, a);
  ln4_relu(a, ln3g, ln3b);
  mm4(a, l3w, l3b, t);
  #pragma unroll
  for (int j = 0; j < 4; ++j) p_table[r * 4 + j] = t[j];
}

// ---------------------------------------------------------------------------
// bias_expand: p_table (465x4) -> dense bias_exp[h][q][k] f32, PRE-SCALED by
// 1/ln2 so the kernel's softmax is a single v_exp (exp2) per score.
// ---------------------------------------------------------------------------
__global__ void bias_expand_kernel(const float* __restrict__ p_table, float* __restrict__ bias_exp) {
  int gid = blockIdx.x * 256 + threadIdx.x;   // 16384 float4's
  int h   = gid >> 12;
  int rem = gid & 4095;
  int q   = rem >> 5;
  int k0  = (rem & 31) * 4;
  int qih = q >> 3, qiw = q & 7;
  float o[4];
  #pragma unroll
  for (int kk = 0; kk < 4; ++kk) {
    int k = k0 + kk;
    int ridx = (qih - (k >> 3) + 15) * 15 + (qiw - (k & 7) + 7);
    o[kk] = p_table[ridx * 4 + h] * INV_LN2;
  }
  f32x4 v = {o[0], o[1], o[2], o[3]};
  *(f32x4*)(bias_exp + gid * 4) = v;
}

// ---------------------------------------------------------------------------
// prep_w: weight frag images. image[slot][lane][j] = w[k = 32*(slot&1) +
// 8*(lane>>4) + j][col = 16*(slot>>1) + (lane&15)].  Serves BOTH as B-frag
// of W (col=lane&15) and A-frag of W^T (row=lane&15).
// q columns scaled by d^-0.5 / ln2 (exp2 folding).
// ---------------------------------------------------------------------------
__global__ void prep_w_kernel(const float* __restrict__ qkv_w, const float* __restrict__ proj_w,
                              short* __restrict__ wqkvF, short* __restrict__ projF) {
  int t = blockIdx.x * 256 + threadIdx.x;    // 16384
  if (t < 12288) {
    int slot = t >> 9, e = t & 511;
    int lp = e >> 3, j = e & 7;
    int ng = slot >> 1, s = slot & 1;
    int k   = 32 * s + 8 * (lp >> 4) + j;
    int col = 16 * ng + (lp & 15);
    float v = qkv_w[k * 192 + col];
    if (col < 64) v *= 0.25f * INV_LN2;
    wqkvF[t] = to_bf16(v);
  } else {
    int t2 = t - 12288;
    int slot = t2 >> 9, e = t2 & 511;
    int lp = e >> 3, j = e & 7;
    int ng = slot >> 1, s = slot & 1;
    int k   = 32 * s + 8 * (lp >> 4) + j;
    int col = 16 * ng + (lp & 15);
    projF[t2] = to_bf16(proj_w[k * 64 + col]);
  }
}

// ---------------------------------------------------------------------------
// prep_mlp_w (unchanged)
// ---------------------------------------------------------------------------
__global__ void prep_mlp_w_kernel(const float* __restrict__ fx1w, const float* __restrict__ fy1w,
                                  const float* __restrict__ fx2w, const float* __restrict__ fy2w,
                                  short* __restrict__ mlpW) {
  int gid = blockIdx.x * 256 + threadIdx.x;   // 65536
  int img = gid >> 14;
  int e   = gid & 16383;
  int slot = e >> 9, lp = (e >> 3) & 63, j = e & 7;
  float v;
  if (img < 2) {
    const float* w1 = img ? fy1w : fx1w;      // (64 x 256)
    int nt = slot >> 1, ks = slot & 1;
    int in_ch = ks * 32 + ((lp >> 4) << 3) + j;
    int hid   = nt * 16 + (lp & 15);
    v = w1[in_ch * HIDN + hid];
  } else {
    const float* w2 = (img & 1) ? fy2w : fx2w; // (256 x 64)
    int nt2 = slot >> 3, g2 = slot & 7;
    int hid = g2 * 32 + ((lp >> 4) << 3) + j;
    int oc  = nt2 * 16 + (lp & 15);
    v = w2[hid * CC + oc];
  }
  mlpW[gid] = to_bf16(v);
}

// ---------------------------------------------------------------------------
// Kernel W v3e: round-9/14 structure + T5 s_setprio around MFMA clusters.
// ---------------------------------------------------------------------------

#define ATT_LOADB(biasreg, qt) { \
  _Pragma("unroll") \
  for (int kt_ = 0; kt_ < 8; ++kt_) \
    biasreg[kt_] = *(const f32x4*)(biasH + (16 * (qt) + l15) * 128 + 16 * kt_ + 4 * lg); }

#define ATT_LOADQ(qfreg, qt) { \
  qfreg = (bf16x8){0, 0, 0, 0, 0, 0, 0, 0}; \
  if (l < 32) { \
    int row_ = 16 * (qt) + l15; \
    qfreg = *(const bf16x8*)(QB_ + ((row_ * 128 + h * 32 + lg * 16) ^ ((row_ & 7) << 4))); } }

#define ATT_BODY(qt, biasreg, qfreg) { \
  f32x4 s_[8]; \
  __builtin_amdgcn_s_setprio(1); \
  _Pragma("unroll") \
  for (int kt_ = 0; kt_ < 8; ++kt_) \
    s_[kt_] = __builtin_amdgcn_mfma_f32_16x16x32_bf16(kf[kt_], qfreg, biasreg[kt_], 0, 0, 0); \
  __builtin_amdgcn_s_setprio(0); \
  float sum_ = 0.0f; \
  _Pragma("unroll") \
  for (int kt_ = 0; kt_ < 8; ++kt_) { \
    s_[kt_][0] = __builtin_amdgcn_exp2f(s_[kt_][0]); \
    s_[kt_][1] = __builtin_amdgcn_exp2f(s_[kt_][1]); \
    s_[kt_][2] = __builtin_amdgcn_exp2f(s_[kt_][2]); \
    s_[kt_][3] = __builtin_amdgcn_exp2f(s_[kt_][3]); \
    sum_ += (s_[kt_][0] + s_[kt_][1]) + (s_[kt_][2] + s_[kt_][3]); } \
  sum_ += __shfl_xor(sum_, 16); \
  sum_ += __shfl_xor(sum_, 32); \
  float inv_ = 1.0f / sum_; \
  _Pragma("unroll") \
  for (int kt_ = 0; kt_ < 8; ++kt_) { \
    int k0_ = 16 * kt_ + 4 * lg; \
    *(bf16x4*)(PBw + ((l15 * 256 + k0_ * 2) ^ pswz)) = mk4_bf16(s_[kt_][0], s_[kt_][1], s_[kt_][2], s_[kt_][3]); } \
  f32x4 pacc_ = {0.0f, 0.0f, 0.0f, 0.0f}; \
  __builtin_amdgcn_s_setprio(1); \
  _Pragma("unroll") \
  for (int ks_ = 0; ks_ < 4; ++ks_) { \
    bf16x8 pa_ = *(const bf16x8*)(PBw + ((l15 * 256 + ks_ * 64 + lg * 16) ^ pswz)); \
    pacc_ = __builtin_amdgcn_mfma_f32_16x16x32_bf16(vf[ks_], pa_, pacc_, 0, 0, 0); } \
  __builtin_amdgcn_s_setprio(0); \
  pacc_[0] *= inv_; pacc_[1] *= inv_; pacc_[2] *= inv_; pacc_[3] *= inv_; \
  *(bf16x4*)(TOK_ + (((16 * (qt) + l15) * 128 + (h * 16 + lg * 4) * 2) ^ (((16 * (qt) + l15) & 7) << 4))) \
      = mk4_bf16(pacc_[0], pacc_[1], pacc_[2], pacc_[3]); }

__launch_bounds__(256, 2)
__global__ void win_attn_kernel(const float* __restrict__ x, const float* __restrict__ y,
                                const float* __restrict__ n1g, const float* __restrict__ n1b,
                                const float* __restrict__ qkv_b, const float* __restrict__ proj_b,
                                const float* __restrict__ bias_exp,
                                const short* __restrict__ wqkvF, const short* __restrict__ projF,
                                float* __restrict__ out) {
  __shared__ __align__(16) char smem[81920];
  char* const TOK_ = smem;            // 16 KB [128 tok][64 ch] bf16 (LN'd; later attn-out)
  char* const QB_  = smem + 16384;    // 16 KB [128 tok][64 d] bf16
  char* const KB_  = smem + 32768;    // 16 KB [128 tok][64 d] bf16
  char* const VT_  = smem + 49152;    // 16 KB [64 d][128 tok] bf16
  char* const PB_  = smem + 65536;    // 16 KB (4 KB per wave) [16 q][128 k] bf16

  const int tid = threadIdx.x;
  const int l   = tid & 63;
  const int l15 = l & 15;
  const int lg  = l >> 4;
  const int wv  = __builtin_amdgcn_readfirstlane(tid >> 6);

  const int widx = blockIdx.x;
  const int b  = widx >> 10;
  const int wl = widx & 1023;
  const int wh = wl >> 5, ww = wl & 31;

  // ---- phase 1: gather + LN -> bf16 token tile (row-swizzled) ----
  {
    const int lane16 = tid & 15;
    const float4 g4 = *(const float4*)(n1g + lane16 * 4);
    const float4 b4 = *(const float4*)(n1b + lane16 * 4);
    #pragma unroll
    for (int ps = 0; ps < 8; ++ps) {
      int t  = ps * 16 + (tid >> 4);
      int g  = t & 63;
      const float* src = ((t & 64) ? y : x)
          + ((long long)b * LL + (long long)(wh * GG + (g >> 3)) * W0c + (ww * GG + (g & 7))) * CC
          + lane16 * 4;
      float4 v = *(const float4*)src;
      float s  = v.x + v.y + v.z + v.w;
      float s2 = v.x * v.x + v.y * v.y + v.z * v.z + v.w * v.w;
      #pragma unroll
      for (int m = 1; m < 16; m <<= 1) { s += __shfl_xor(s, m); s2 += __shfl_xor(s2, m); }
      float mu  = s * (1.0f / 64.0f);
      float var = fmaxf(s2 * (1.0f / 64.0f) - mu * mu, 0.0f);
      float rs  = rsqrtf(var + 1e-5f);
      bf16x4 w4 = mk4_bf16((v.x - mu) * rs * g4.x + b4.x,
                           (v.y - mu) * rs * g4.y + b4.y,
                           (v.z - mu) * rs * g4.z + b4.z,
                           (v.w - mu) * rs * g4.w + b4.w);
      *(bf16x4*)(TOK_ + ((t * 128 + lane16 * 8) ^ ((t & 7) << 4))) = w4;
    }
  }
  __syncthreads();

  // ---- phase 2: QKV. waves 0,1 -> Q^T (32 ch each); waves 2,3 -> K^T;
  //      every wave also one 16-ch V tile. One TOK read feeds both. ----
  {
    bf16x8 awq[2][2];                   // A-frags of W^T (Q or K half)
    #pragma unroll
    for (int ct = 0; ct < 2; ++ct)
      #pragma unroll
      for (int ks = 0; ks < 2; ++ks)
        awq[ct][ks] = *(const bf16x8*)((const char*)wqkvF + ((((2 * wv + ct) * 2 + ks)) << 10) + l * 16);
    bf16x8 bwv[2];                      // B-frags of W_v tile
    #pragma unroll
    for (int ks = 0; ks < 2; ++ks)
      bwv[ks] = *(const bf16x8*)((const char*)wqkvF + (((8 + wv) * 2 + ks) << 10) + l * 16);

    f32x4 bq[2];
    #pragma unroll
    for (int ct = 0; ct < 2; ++ct) {
      f32x4 bb = *(const f32x4*)(qkv_b + (2 * wv + ct) * 16 + lg * 4);
      if (wv < 2) {
        const float qs = 0.25f * INV_LN2;
        bb[0] *= qs; bb[1] *= qs; bb[2] *= qs; bb[3] *= qs;
      }
      bq[ct] = bb;
    }
    const float bv = qkv_b[128 + wv * 16 + l15];
    char* const QKbuf = (wv < 2) ? QB_ : KB_;
    const int chv = wv * 16 + l15;        // V d-row in VT
    const int vswz = (chv & 7) << 4;

    #pragma unroll
    for (int nt = 0; nt < 8; ++nt) {
      const int row = 16 * nt + l15;
      const int rswz = (row & 7) << 4;
      bf16x8 t0 = *(const bf16x8*)(TOK_ + ((row * 128 +  0 + lg * 16) ^ rswz));
      bf16x8 t1 = *(const bf16x8*)(TOK_ + ((row * 128 + 64 + lg * 16) ^ rswz));
      __builtin_amdgcn_s_setprio(1);
      // Q^T / K^T: D col=token(l15), row=4 consecutive d
      f32x4 a0 = bq[0];
      a0 = __builtin_amdgcn_mfma_f32_16x16x32_bf16(awq[0][0], t0, a0, 0, 0, 0);
      a0 = __builtin_amdgcn_mfma_f32_16x16x32_bf16(awq[0][1], t1, a0, 0, 0, 0);
      f32x4 a1 = bq[1];
      a1 = __builtin_amdgcn_mfma_f32_16x16x32_bf16(awq[1][0], t0, a1, 0, 0, 0);
      a1 = __builtin_amdgcn_mfma_f32_16x16x32_bf16(awq[1][1], t1, a1, 0, 0, 0);
      f32x4 av = {bv, bv, bv, bv};
      av = __builtin_amdgcn_mfma_f32_16x16x32_bf16(t0, bwv[0], av, 0, 0, 0);
      av = __builtin_amdgcn_mfma_f32_16x16x32_bf16(t1, bwv[1], av, 0, 0, 0);
      __builtin_amdgcn_s_setprio(0);
      {
        int chL = (((2 * wv + 0) * 16) & 63) + lg * 4;
        *(bf16x4*)(QKbuf + ((row * 128 + chL * 2) ^ rswz)) = mk4_bf16(a0[0], a0[1], a0[2], a0[3]);
        chL = (((2 * wv + 1) * 16) & 63) + lg * 4;
        *(bf16x4*)(QKbuf + ((row * 128 + chL * 2) ^ rswz)) = mk4_bf16(a1[0], a1[1], a1[2], a1[3]);
      }
      {
        int tok0 = 16 * nt + lg * 4;
        *(bf16x4*)(VT_ + ((chv * 256 + tok0 * 2) ^ vswz)) = mk4_bf16(av[0], av[1], av[2], av[3]);
      }
    }
  }
  __syncthreads();

  // ---- phase 3: attention, wave = head.  S^T = K x Q (swapped). ----
  {
    const int h = wv;
    const float* biasH = bias_exp + h * 16384;
    bf16x8 kf[8];
    #pragma unroll
    for (int kt = 0; kt < 8; ++kt) {
      bf16x8 f = {0, 0, 0, 0, 0, 0, 0, 0};
      if (l < 32) {
        int row = 16 * kt + l15;
        f = *(const bf16x8*)(KB_ + ((row * 128 + h * 32 + lg * 16) ^ ((row & 7) << 4)));
      }
      kf[kt] = f;
    }
    bf16x8 vf[4];                       // VT rows h*16+l15 (A-frag: row=d, k=tok)
    #pragma unroll
    for (int ks = 0; ks < 4; ++ks) {
      int row = h * 16 + l15;
      vf[ks] = *(const bf16x8*)(VT_ + ((row * 256 + ks * 64 + lg * 16) ^ ((row & 7) << 4)));
    }
    char* const PBw = PB_ + wv * 4096;
    const int pswz = (l15 & 7) << 4;

    // 2-stage pipeline: bias (global) + qf (LDS) prefetched one qt ahead.
    f32x4 biasE[8], biasO[8];
    bf16x8 qfE, qfO;
    ATT_LOADB(biasE, 0);
    ATT_LOADQ(qfE, 0);
    #pragma unroll
    for (int qq = 0; qq < 4; ++qq) {
      ATT_LOADB(biasO, 2 * qq + 1);
      ATT_LOADQ(qfO, 2 * qq + 1);
      ATT_BODY(2 * qq, biasE, qfE);
      if (qq < 3) {
        ATT_LOADB(biasE, 2 * qq + 2);
        ATT_LOADQ(qfE, 2 * qq + 2);
      }
      ATT_BODY(2 * qq + 1, biasO, qfO);
    }
  }
  __syncthreads();

  // ---- phase 4: proj^T (A = proj_w^T image, B = attn-out) + residual ----
  {
    bf16x8 pa2[2];
    #pragma unroll
    for (int ks = 0; ks < 2; ++ks)
      pa2[ks] = *(const bf16x8*)((const char*)projF + (((wv * 2 + ks)) << 10) + l * 16);
    const f32x4 bp = *(const f32x4*)(proj_b + wv * 16 + lg * 4);
    #pragma unroll
    for (int nt = 0; nt < 8; ++nt) {
      const int row = 16 * nt + l15;       // token
      const int rswz = (row & 7) << 4;
      bf16x8 t0 = *(const bf16x8*)(TOK_ + ((row * 128 +  0 + lg * 16) ^ rswz));
      bf16x8 t1 = *(const bf16x8*)(TOK_ + ((row * 128 + 64 + lg * 16) ^ rswz));
      f32x4 acc = bp;
      __builtin_amdgcn_s_setprio(1);
      acc = __builtin_amdgcn_mfma_f32_16x16x32_bf16(pa2[0], t0, acc, 0, 0, 0);
      acc = __builtin_amdgcn_mfma_f32_16x16x32_bf16(pa2[1], t1, acc, 0, 0, 0);
      __builtin_amdgcn_s_setprio(0);
      // D col=token(l15), row=4 consecutive out-ch -> dwordx4 residual
      int g = row & 63;
      long long base = ((long long)b * LL + (long long)(wh * GG + (g >> 3)) * W0c + (ww * GG + (g & 7))) * CC
                       + wv * 16 + lg * 4;
      const float* src = ((row & 64) ? y : x) + base;
      float* dst = out + ((row & 64) ? MODSZ : 0) + base;
      f32x4 sv = *(const f32x4*)src;
      sv[0] += acc[0]; sv[1] += acc[1]; sv[2] += acc[2]; sv[3] += acc[3];
      *(f32x4*)dst = sv;
    }
  }
}

// ---------------------------------------------------------------------------
// Kernel M v2: transposed-operand MFMA MLP + T5 setprio on MFMA clusters
// ---------------------------------------------------------------------------
__launch_bounds__(256, 3)
__global__ void mlp_mfma_kernel(const float* __restrict__ n2g, const float* __restrict__ n2b,
                                const float* __restrict__ fx1b, const float* __restrict__ fx2b,
                                const float* __restrict__ fy1b, const float* __restrict__ fy2b,
                                const short* __restrict__ mlpW, float* __restrict__ out) {
  __shared__ __align__(16) char AR4[4][8192];

  const int tid = threadIdx.x;
  const int l   = tid & 63;
  const int l15 = l & 15;
  const int lg  = l >> 4;
  const int wv  = tid >> 6;
  const int bid = blockIdx.x;
  const int mod = bid >> 10;                         // 0=x, 1=y
  const long long wtok0 = (long long)(bid & 1023) * 128 + wv * 32;

  const float* b1 = mod ? fy1b : fx1b;
  const float* b2 = mod ? fy2b : fx2b;
  const short* w1T = mlpW + mod * 16384;
  const short* w2T = mlpW + 32768 + mod * 16384;
  float* const outm = out + (long long)mod * MODSZ;

  char* const TOKw = AR4[wv];            // 32 rows, stride 144 B
  char* const HBw  = AR4[wv] + 4608;     // 32 rows, stride 80 B

  {
    const f32x4 g4 = *(const f32x4*)(n2g + l15 * 4);
    const f32x4 b4 = *(const f32x4*)(n2b + l15 * 4);
    #pragma unroll
    for (int ps = 0; ps < 8; ++ps) {
      int t = ps * 4 + lg;
      const float* rp = outm + (wtok0 + t) * CC + l15 * 4;
      f32x4 v = *(const f32x4*)rp;
      float s  = v[0] + v[1] + v[2] + v[3];
      float s2 = v[0] * v[0] + v[1] * v[1] + v[2] * v[2] + v[3] * v[3];
      #pragma unroll
      for (int m = 1; m < 16; m <<= 1) { s += __shfl_xor(s, m); s2 += __shfl_xor(s2, m); }
      float mu  = s * (1.0f / 64.0f);
      float var = fmaxf(s2 * (1.0f / 64.0f) - mu * mu, 0.0f);
      float rs  = rsqrtf(var + 1e-5f);
      bf16x4 w4 = mk4_bf16((v[0] - mu) * rs * g4[0] + b4[0],
                           (v[1] - mu) * rs * g4[1] + b4[1],
                           (v[2] - mu) * rs * g4[2] + b4[2],
                           (v[3] - mu) * rs * g4[3] + b4[3]);
      *(bf16x4*)(TOKw + t * 144 + l15 * 8) = w4;
    }
  }

  bf16x8 tokB[2][2];
  #pragma unroll
  for (int ct = 0; ct < 2; ++ct)
    #pragma unroll
    for (int ks = 0; ks < 2; ++ks)
      tokB[ct][ks] = *(const bf16x8*)(TOKw + (16 * ct + l15) * 144 + ks * 64 + lg * 16);

  f32x4 acc2[4][2];
  #pragma unroll
  for (int n = 0; n < 4; ++n) {
    f32x4 bb = *(const f32x4*)(b2 + n * 16 + lg * 4);
    acc2[n][0] = bb; acc2[n][1] = bb;
  }

  #pragma unroll 1
  for (int g2 = 0; g2 < 8; ++g2) {
    #pragma unroll
    for (int sub = 0; sub < 2; ++sub) {
      const int nt = g2 * 2 + sub;
      bf16x8 wa0 = *(const bf16x8*)(w1T + ((nt * 2 + 0) << 9) + l * 8);
      bf16x8 wa1 = *(const bf16x8*)(w1T + ((nt * 2 + 1) << 9) + l * 8);
      f32x4 z = {0.0f, 0.0f, 0.0f, 0.0f};
      __builtin_amdgcn_s_setprio(1);
      f32x4 d0 = __builtin_amdgcn_mfma_f32_16x16x32_bf16(wa0, tokB[0][0], z, 0, 0, 0);
      d0 = __builtin_amdgcn_mfma_f32_16x16x32_bf16(wa1, tokB[0][1], d0, 0, 0, 0);
      f32x4 d1 = __builtin_amdgcn_mfma_f32_16x16x32_bf16(wa0, tokB[1][0], z, 0, 0, 0);
      d1 = __builtin_amdgcn_mfma_f32_16x16x32_bf16(wa1, tokB[1][1], d1, 0, 0, 0);
      __builtin_amdgcn_s_setprio(0);
      f32x4 b1v = *(const f32x4*)(b1 + nt * 16 + lg * 4);
      bf16x4 h0 = mk4_bf16(gelu_tanh(d0[0] + b1v[0]), gelu_tanh(d0[1] + b1v[1]),
                           gelu_tanh(d0[2] + b1v[2]), gelu_tanh(d0[3] + b1v[3]));
      bf16x4 h1 = mk4_bf16(gelu_tanh(d1[0] + b1v[0]), gelu_tanh(d1[1] + b1v[1]),
                           gelu_tanh(d1[2] + b1v[2]), gelu_tanh(d1[3] + b1v[3]));
      *(bf16x4*)(HBw + l15 * 80        + sub * 32 + lg * 8) = h0;
      *(bf16x4*)(HBw + (16 + l15) * 80 + sub * 32 + lg * 8) = h1;
    }
    bf16x8 hb0 = *(const bf16x8*)(HBw + l15 * 80        + lg * 16);
    bf16x8 hb1 = *(const bf16x8*)(HBw + (16 + l15) * 80 + lg * 16);
    __builtin_amdgcn_s_setprio(1);
    #pragma unroll
    for (int n = 0; n < 4; ++n) {
      bf16x8 wa = *(const bf16x8*)(w2T + ((n * 8 + g2) << 9) + l * 8);
      acc2[n][0] = __builtin_amdgcn_mfma_f32_16x16x32_bf16(wa, hb0, acc2[n][0], 0, 0, 0);
      acc2[n][1] = __builtin_amdgcn_mfma_f32_16x16x32_bf16(wa, hb1, acc2[n][1], 0, 0, 0);
    }
    __builtin_amdgcn_s_setprio(0);
  }

  #pragma unroll
  for (int n = 0; n < 4; ++n)
    #pragma unroll
    for (int ct = 0; ct < 2; ++ct) {
      float* rp = outm + (wtok0 + 16 * ct + l15) * CC + n * 16 + lg * 4;
      f32x4 o = *(const f32x4*)rp;
      o[0] += acc2[n][ct][0]; o[1] += acc2[n][ct][1];
      o[2] += acc2[n][ct][2]; o[3] += acc2[n][ct][3];
      *(f32x4*)rp = o;
    }
}

// ---------------------------------------------------------------------------
extern "C" void kernel_launch(void* const* d_in, const int* in_sizes, int n_in,
                              void* d_out, int out_size, void* d_ws, size_t ws_size,
                              hipStream_t stream) {
  const float* x      = (const float*)d_in[0];
  const float* y      = (const float*)d_in[1];
  const float* n1g    = (const float*)d_in[2];
  const float* n1b    = (const float*)d_in[3];
  const float* qkv_w  = (const float*)d_in[4];
  const float* qkv_b  = (const float*)d_in[5];
  const float* proj_w = (const float*)d_in[6];
  const float* proj_b = (const float*)d_in[7];
  const float* pp_w   = (const float*)d_in[8];
  const float* pp_b   = (const float*)d_in[9];
  const float* ln1g   = (const float*)d_in[10];
  const float* ln1b   = (const float*)d_in[11];
  const float* l1w    = (const float*)d_in[12];
  const float* l1b    = (const float*)d_in[13];
  const float* ln2g   = (const float*)d_in[14];
  const float* ln2b   = (const float*)d_in[15];
  const float* l2w    = (const float*)d_in[16];
  const float* l2b    = (const float*)d_in[17];
  const float* ln3g   = (const float*)d_in[18];
  const float* ln3b   = (const float*)d_in[19];
  const float* l3w    = (const float*)d_in[20];
  const float* l3b    = (const float*)d_in[21];
  const float* n2g    = (const float*)d_in[22];
  const float* n2b    = (const float*)d_in[23];
  const float* fx1w   = (const float*)d_in[24];
  const float* fx1b   = (const float*)d_in[25];
  const float* fx2w   = (const float*)d_in[26];
  const float* fx2b   = (const float*)d_in[27];
  const float* fy1w   = (const float*)d_in[28];
  const float* fy1b   = (const float*)d_in[29];
  const float* fy2w   = (const float*)d_in[30];
  const float* fy2b   = (const float*)d_in[31];
  (void)in_sizes; (void)n_in; (void)out_size; (void)ws_size;

  float* out = (float*)d_out;
  char*  ws  = (char*)d_ws;
  float* p_table  = (float*)(ws + WS_PTAB);
  float* bias_exp = (float*)(ws + WS_BIAS);
  short* wqkvF    = (short*)(ws + WS_WQKV);
  short* projF    = (short*)(ws + WS_WPROJ);
  short* mlpW     = (short*)(ws + WS_MLPW);

  pbias_kernel<<<1, 512, 0, stream>>>(pp_w, pp_b, ln1g, ln1b, l1w, l1b,
                                      ln2g, ln2b, l2w, l2b, ln3g, ln3b, l3w, l3b, p_table);
  bias_expand_kernel<<<64, 256, 0, stream>>>(p_table, bias_exp);
  prep_w_kernel<<<64, 256, 0, stream>>>(qkv_w, proj_w, wqkvF, projF);
  prep_mlp_w_kernel<<<256, 256, 0, stream>>>(fx1w, fy1w, fx2w, fy2w, mlpW);
  win_attn_kernel<<<NWIN, 256, 0, stream>>>(x, y, n1g, n1b, qkv_b, proj_b,
                                            bias_exp, wqkvF, projF, out);
  mlp_mfma_kernel<<<2048, 256, 0, stream>>>(n2g, n2b, fx1b, fx2b, fy1b, fy2b,
                                            mlpW, out);
}

// Round 16
// 169.047 us; speedup vs baseline: 1.0431x; 1.0431x over previous
//
#include <hip/hip_runtime.h>
#include <math.h>

constexpr int CC    = 64;          // channels
constexpr int GG    = 8;           // window size
constexpr int H0    = 256;
constexpr int W0c   = 256;
constexpr int BB    = 2;
constexpr int LL    = H0 * W0c;                     // 65536
constexpr int NWIN  = BB * (H0 / GG) * (W0c / GG);  // 2048
constexpr int HIDN  = 256;                          // MLP hidden
constexpr int NBIA  = 31 * 15;                      // 465 relative-pos entries
constexpr long long MODSZ = (long long)BB * LL * CC; // 8388608 floats per modality

constexpr float INV_LN2 = 1.4426950408889634f;

// ws byte offsets
constexpr int WS_PTAB  = 0;        // 465*4 f32
constexpr int WS_BIAS  = 8192;     // [4][128][128] f32 = 256 KB (pre-scaled by 1/ln2)
constexpr int WS_WQKV  = 270336;   // 24 slots * 512 bf16 = 24 KB (frag image)
constexpr int WS_WPROJ = 294912;   // 8 slots * 512 bf16 = 8 KB
constexpr int WS_MLPW  = 303104;   // 4 images * 16384 bf16 = 128 KB (A-frag images)

using f32x4  = __attribute__((ext_vector_type(4))) float;
using bf16x8 = __attribute__((ext_vector_type(8))) short;
using bf16x4 = __attribute__((ext_vector_type(4))) short;

static __device__ __forceinline__ short to_bf16(float f) {   // RNE (prep kernels)
  unsigned u = __float_as_uint(f);
  unsigned r = (u + 0x7FFFu + ((u >> 16) & 1u)) >> 16;
  return (short)r;
}
// hot-path packing: round-half-up, pair-packed in pure C (no asm — round-5 lesson)
static __device__ __forceinline__ bf16x4 mk4_bf16(float a, float b, float c, float d) {
  unsigned p0 = ((__float_as_uint(a) + 0x8000u) >> 16) | ((__float_as_uint(b) + 0x8000u) & 0xFFFF0000u);
  unsigned p1 = ((__float_as_uint(c) + 0x8000u) >> 16) | ((__float_as_uint(d) + 0x8000u) & 0xFFFF0000u);
  bf16x4 r;
  r[0] = (short)(p0 & 0xFFFFu); r[1] = (short)(p0 >> 16);
  r[2] = (short)(p1 & 0xFFFFu); r[3] = (short)(p1 >> 16);
  return r;
}
static __device__ __forceinline__ float gelu_tanh(float u) {
  float u2 = u * u;
  float t  = fmaf(0.044715f, u2, 1.0f);
  float z  = u * t * 1.5957691216057308f;
  float e  = __expf(-z);
  return u / (1.0f + e);
}

// ---------------------------------------------------------------------------
// Kernel P: dynamic position bias table (465 x 4) via tiny MLP
// ---------------------------------------------------------------------------
static __device__ __forceinline__ void ln4_relu(float* p, const float* g, const float* b) {
  float mu = 0.25f * (p[0] + p[1] + p[2] + p[3]);
  float d0 = p[0] - mu, d1 = p[1] - mu, d2 = p[2] - mu, d3 = p[3] - mu;
  float var = 0.25f * (d0 * d0 + d1 * d1 + d2 * d2 + d3 * d3);
  float rs = rsqrtf(var + 1e-5f);
  p[0] = fmaxf(d0 * rs * g[0] + b[0], 0.0f);
  p[1] = fmaxf(d1 * rs * g[1] + b[1], 0.0f);
  p[2] = fmaxf(d2 * rs * g[2] + b[2], 0.0f);
  p[3] = fmaxf(d3 * rs * g[3] + b[3], 0.0f);
}
static __device__ __forceinline__ void mm4(const float* a, const float* w, const float* b, float* o) {
  #pragma unroll
  for (int j = 0; j < 4; ++j) {
    float s = b[j];
    #pragma unroll
    for (int i = 0; i < 4; ++i) s += a[i] * w[i * 4 + j];
    o[j] = s;
  }
}

__global__ void pbias_kernel(const float* __restrict__ pp_w, const float* __restrict__ pp_b,
                             const float* __restrict__ ln1g, const float* __restrict__ ln1b,
                             const float* __restrict__ l1w,  const float* __restrict__ l1b,
                             const float* __restrict__ ln2g, const float* __restrict__ ln2b,
                             const float* __restrict__ l2w,  const float* __restrict__ l2b,
                             const float* __restrict__ ln3g, const float* __restrict__ ln3b,
                             const float* __restrict__ l3w,  const float* __restrict__ l3b,
                             float* __restrict__ p_table) {
  int r = blockIdx.x * blockDim.x + threadIdx.x;
  if (r >= NBIA) return;
  float bh = (float)(r / 15 - 15);
  float bw = (float)(r % 15 - 7);
  float a[4], t[4];
  #pragma unroll
  for (int j = 0; j < 4; ++j) a[j] = bh * pp_w[j] + bw * pp_w[4 + j] + pp_b[j];
  ln4_relu(a, ln1g, ln1b);
  mm4(a, l1w, l1b, t);
  ln4_relu(t, ln2g, ln2b);
  mm4(t, l2w, l2b, a);
  ln4_relu(a, ln3g, ln3b);
  mm4(a, l3w, l3b, t);
  #pragma unroll
  for (int j = 0; j < 4; ++j) p_table[r * 4 + j] = t[j];
}

// ---------------------------------------------------------------------------
// bias_expand: p_table (465x4) -> dense bias_exp[h][q][k] f32, PRE-SCALED by
// 1/ln2 so the kernel's softmax is a single v_exp (exp2) per score.
// ---------------------------------------------------------------------------
__global__ void bias_expand_kernel(const float* __restrict__ p_table, float* __restrict__ bias_exp) {
  int gid = blockIdx.x * 256 + threadIdx.x;   // 16384 float4's
  int h   = gid >> 12;
  int rem = gid & 4095;
  int q   = rem >> 5;
  int k0  = (rem & 31) * 4;
  int qih = q >> 3, qiw = q & 7;
  float o[4];
  #pragma unroll
  for (int kk = 0; kk < 4; ++kk) {
    int k = k0 + kk;
    int ridx = (qih - (k >> 3) + 15) * 15 + (qiw - (k & 7) + 7);
    o[kk] = p_table[ridx * 4 + h] * INV_LN2;
  }
  f32x4 v = {o[0], o[1], o[2], o[3]};
  *(f32x4*)(bias_exp + gid * 4) = v;
}

// ---------------------------------------------------------------------------
// prep_w: weight frag images. image[slot][lane][j] = w[k = 32*(slot&1) +
// 8*(lane>>4) + j][col = 16*(slot>>1) + (lane&15)].  Serves BOTH as B-frag
// of W (col=lane&15) and A-frag of W^T (row=lane&15).
// q columns scaled by d^-0.5 / ln2 (exp2 folding).
// ---------------------------------------------------------------------------
__global__ void prep_w_kernel(const float* __restrict__ qkv_w, const float* __restrict__ proj_w,
                              short* __restrict__ wqkvF, short* __restrict__ projF) {
  int t = blockIdx.x * 256 + threadIdx.x;    // 16384
  if (t < 12288) {
    int slot = t >> 9, e = t & 511;
    int lp = e >> 3, j = e & 7;
    int ng = slot >> 1, s = slot & 1;
    int k   = 32 * s + 8 * (lp >> 4) + j;
    int col = 16 * ng + (lp & 15);
    float v = qkv_w[k * 192 + col];
    if (col < 64) v *= 0.25f * INV_LN2;
    wqkvF[t] = to_bf16(v);
  } else {
    int t2 = t - 12288;
    int slot = t2 >> 9, e = t2 & 511;
    int lp = e >> 3, j = e & 7;
    int ng = slot >> 1, s = slot & 1;
    int k   = 32 * s + 8 * (lp >> 4) + j;
    int col = 16 * ng + (lp & 15);
    projF[t2] = to_bf16(proj_w[k * 64 + col]);
  }
}

// ---------------------------------------------------------------------------
// prep_mlp_w (unchanged)
// ---------------------------------------------------------------------------
__global__ void prep_mlp_w_kernel(const float* __restrict__ fx1w, const float* __restrict__ fy1w,
                                  const float* __restrict__ fx2w, const float* __restrict__ fy2w,
                                  short* __restrict__ mlpW) {
  int gid = blockIdx.x * 256 + threadIdx.x;   // 65536
  int img = gid >> 14;
  int e   = gid & 16383;
  int slot = e >> 9, lp = (e >> 3) & 63, j = e & 7;
  float v;
  if (img < 2) {
    const float* w1 = img ? fy1w : fx1w;      // (64 x 256)
    int nt = slot >> 1, ks = slot & 1;
    int in_ch = ks * 32 + ((lp >> 4) << 3) + j;
    int hid   = nt * 16 + (lp & 15);
    v = w1[in_ch * HIDN + hid];
  } else {
    const float* w2 = (img & 1) ? fy2w : fx2w; // (256 x 64)
    int nt2 = slot >> 3, g2 = slot & 7;
    int hid = g2 * 32 + ((lp >> 4) << 3) + j;
    int oc  = nt2 * 16 + (lp & 15);
    v = w2[hid * CC + oc];
  }
  mlpW[gid] = to_bf16(v);
}

// ---------------------------------------------------------------------------
// Kernel W v3d (FINAL, round-9/14 best): shared-LDS Q/K/V buffers, 2-stage
// qt pipeline (bias/qf prefetched one iteration ahead, named even/odd regs).
// ---------------------------------------------------------------------------

#define ATT_LOADB(biasreg, qt) { \
  _Pragma("unroll") \
  for (int kt_ = 0; kt_ < 8; ++kt_) \
    biasreg[kt_] = *(const f32x4*)(biasH + (16 * (qt) + l15) * 128 + 16 * kt_ + 4 * lg); }

#define ATT_LOADQ(qfreg, qt) { \
  qfreg = (bf16x8){0, 0, 0, 0, 0, 0, 0, 0}; \
  if (l < 32) { \
    int row_ = 16 * (qt) + l15; \
    qfreg = *(const bf16x8*)(QB_ + ((row_ * 128 + h * 32 + lg * 16) ^ ((row_ & 7) << 4))); } }

#define ATT_BODY(qt, biasreg, qfreg) { \
  f32x4 s_[8]; \
  _Pragma("unroll") \
  for (int kt_ = 0; kt_ < 8; ++kt_) \
    s_[kt_] = __builtin_amdgcn_mfma_f32_16x16x32_bf16(kf[kt_], qfreg, biasreg[kt_], 0, 0, 0); \
  float sum_ = 0.0f; \
  _Pragma("unroll") \
  for (int kt_ = 0; kt_ < 8; ++kt_) { \
    s_[kt_][0] = __builtin_amdgcn_exp2f(s_[kt_][0]); \
    s_[kt_][1] = __builtin_amdgcn_exp2f(s_[kt_][1]); \
    s_[kt_][2] = __builtin_amdgcn_exp2f(s_[kt_][2]); \
    s_[kt_][3] = __builtin_amdgcn_exp2f(s_[kt_][3]); \
    sum_ += (s_[kt_][0] + s_[kt_][1]) + (s_[kt_][2] + s_[kt_][3]); } \
  sum_ += __shfl_xor(sum_, 16); \
  sum_ += __shfl_xor(sum_, 32); \
  float inv_ = 1.0f / sum_; \
  _Pragma("unroll") \
  for (int kt_ = 0; kt_ < 8; ++kt_) { \
    int k0_ = 16 * kt_ + 4 * lg; \
    *(bf16x4*)(PBw + ((l15 * 256 + k0_ * 2) ^ pswz)) = mk4_bf16(s_[kt_][0], s_[kt_][1], s_[kt_][2], s_[kt_][3]); } \
  f32x4 pacc_ = {0.0f, 0.0f, 0.0f, 0.0f}; \
  _Pragma("unroll") \
  for (int ks_ = 0; ks_ < 4; ++ks_) { \
    bf16x8 pa_ = *(const bf16x8*)(PBw + ((l15 * 256 + ks_ * 64 + lg * 16) ^ pswz)); \
    pacc_ = __builtin_amdgcn_mfma_f32_16x16x32_bf16(vf[ks_], pa_, pacc_, 0, 0, 0); } \
  pacc_[0] *= inv_; pacc_[1] *= inv_; pacc_[2] *= inv_; pacc_[3] *= inv_; \
  *(bf16x4*)(TOK_ + (((16 * (qt) + l15) * 128 + (h * 16 + lg * 4) * 2) ^ (((16 * (qt) + l15) & 7) << 4))) \
      = mk4_bf16(pacc_[0], pacc_[1], pacc_[2], pacc_[3]); }

__launch_bounds__(256, 2)
__global__ void win_attn_kernel(const float* __restrict__ x, const float* __restrict__ y,
                                const float* __restrict__ n1g, const float* __restrict__ n1b,
                                const float* __restrict__ qkv_b, const float* __restrict__ proj_b,
                                const float* __restrict__ bias_exp,
                                const short* __restrict__ wqkvF, const short* __restrict__ projF,
                                float* __restrict__ out) {
  __shared__ __align__(16) char smem[81920];
  char* const TOK_ = smem;            // 16 KB [128 tok][64 ch] bf16 (LN'd; later attn-out)
  char* const QB_  = smem + 16384;    // 16 KB [128 tok][64 d] bf16
  char* const KB_  = smem + 32768;    // 16 KB [128 tok][64 d] bf16
  char* const VT_  = smem + 49152;    // 16 KB [64 d][128 tok] bf16
  char* const PB_  = smem + 65536;    // 16 KB (4 KB per wave) [16 q][128 k] bf16

  const int tid = threadIdx.x;
  const int l   = tid & 63;
  const int l15 = l & 15;
  const int lg  = l >> 4;
  const int wv  = __builtin_amdgcn_readfirstlane(tid >> 6);

  const int widx = blockIdx.x;
  const int b  = widx >> 10;
  const int wl = widx & 1023;
  const int wh = wl >> 5, ww = wl & 31;

  // ---- phase 1: gather + LN -> bf16 token tile (row-swizzled) ----
  {
    const int lane16 = tid & 15;
    const float4 g4 = *(const float4*)(n1g + lane16 * 4);
    const float4 b4 = *(const float4*)(n1b + lane16 * 4);
    #pragma unroll
    for (int ps = 0; ps < 8; ++ps) {
      int t  = ps * 16 + (tid >> 4);
      int g  = t & 63;
      const float* src = ((t & 64) ? y : x)
          + ((long long)b * LL + (long long)(wh * GG + (g >> 3)) * W0c + (ww * GG + (g & 7))) * CC
          + lane16 * 4;
      float4 v = *(const float4*)src;
      float s  = v.x + v.y + v.z + v.w;
      float s2 = v.x * v.x + v.y * v.y + v.z * v.z + v.w * v.w;
      #pragma unroll
      for (int m = 1; m < 16; m <<= 1) { s += __shfl_xor(s, m); s2 += __shfl_xor(s2, m); }
      float mu  = s * (1.0f / 64.0f);
      float var = fmaxf(s2 * (1.0f / 64.0f) - mu * mu, 0.0f);
      float rs  = rsqrtf(var + 1e-5f);
      bf16x4 w4 = mk4_bf16((v.x - mu) * rs * g4.x + b4.x,
                           (v.y - mu) * rs * g4.y + b4.y,
                           (v.z - mu) * rs * g4.z + b4.z,
                           (v.w - mu) * rs * g4.w + b4.w);
      *(bf16x4*)(TOK_ + ((t * 128 + lane16 * 8) ^ ((t & 7) << 4))) = w4;
    }
  }
  __syncthreads();

  // ---- phase 2: QKV. waves 0,1 -> Q^T (32 ch each); waves 2,3 -> K^T;
  //      every wave also one 16-ch V tile. One TOK read feeds both. ----
  {
    bf16x8 awq[2][2];                   // A-frags of W^T (Q or K half)
    #pragma unroll
    for (int ct = 0; ct < 2; ++ct)
      #pragma unroll
      for (int ks = 0; ks < 2; ++ks)
        awq[ct][ks] = *(const bf16x8*)((const char*)wqkvF + ((((2 * wv + ct) * 2 + ks)) << 10) + l * 16);
    bf16x8 bwv[2];                      // B-frags of W_v tile
    #pragma unroll
    for (int ks = 0; ks < 2; ++ks)
      bwv[ks] = *(const bf16x8*)((const char*)wqkvF + (((8 + wv) * 2 + ks) << 10) + l * 16);

    f32x4 bq[2];
    #pragma unroll
    for (int ct = 0; ct < 2; ++ct) {
      f32x4 bb = *(const f32x4*)(qkv_b + (2 * wv + ct) * 16 + lg * 4);
      if (wv < 2) {
        const float qs = 0.25f * INV_LN2;
        bb[0] *= qs; bb[1] *= qs; bb[2] *= qs; bb[3] *= qs;
      }
      bq[ct] = bb;
    }
    const float bv = qkv_b[128 + wv * 16 + l15];
    char* const QKbuf = (wv < 2) ? QB_ : KB_;
    const int chv = wv * 16 + l15;        // V d-row in VT
    const int vswz = (chv & 7) << 4;

    #pragma unroll
    for (int nt = 0; nt < 8; ++nt) {
      const int row = 16 * nt + l15;
      const int rswz = (row & 7) << 4;
      bf16x8 t0 = *(const bf16x8*)(TOK_ + ((row * 128 +  0 + lg * 16) ^ rswz));
      bf16x8 t1 = *(const bf16x8*)(TOK_ + ((row * 128 + 64 + lg * 16) ^ rswz));
      // Q^T / K^T: D col=token(l15), row=4 consecutive d
      #pragma unroll
      for (int ct = 0; ct < 2; ++ct) {
        f32x4 a = bq[ct];
        a = __builtin_amdgcn_mfma_f32_16x16x32_bf16(awq[ct][0], t0, a, 0, 0, 0);
        a = __builtin_amdgcn_mfma_f32_16x16x32_bf16(awq[ct][1], t1, a, 0, 0, 0);
        int chL = (((2 * wv + ct) * 16) & 63) + lg * 4;
        *(bf16x4*)(QKbuf + ((row * 128 + chL * 2) ^ rswz)) = mk4_bf16(a[0], a[1], a[2], a[3]);
      }
      // V: D col=d(l15), row=4 consecutive tokens -> VT row write
      {
        f32x4 a = {bv, bv, bv, bv};
        a = __builtin_amdgcn_mfma_f32_16x16x32_bf16(t0, bwv[0], a, 0, 0, 0);
        a = __builtin_amdgcn_mfma_f32_16x16x32_bf16(t1, bwv[1], a, 0, 0, 0);
        int tok0 = 16 * nt + lg * 4;
        *(bf16x4*)(VT_ + ((chv * 256 + tok0 * 2) ^ vswz)) = mk4_bf16(a[0], a[1], a[2], a[3]);
      }
    }
  }
  __syncthreads();

  // ---- phase 3: attention, wave = head.  S^T = K x Q (swapped). ----
  {
    const int h = wv;
    const float* biasH = bias_exp + h * 16384;
    bf16x8 kf[8];
    #pragma unroll
    for (int kt = 0; kt < 8; ++kt) {
      bf16x8 f = {0, 0, 0, 0, 0, 0, 0, 0};
      if (l < 32) {
        int row = 16 * kt + l15;
        f = *(const bf16x8*)(KB_ + ((row * 128 + h * 32 + lg * 16) ^ ((row & 7) << 4)));
      }
      kf[kt] = f;
    }
    bf16x8 vf[4];                       // VT rows h*16+l15 (A-frag: row=d, k=tok)
    #pragma unroll
    for (int ks = 0; ks < 4; ++ks) {
      int row = h * 16 + l15;
      vf[ks] = *(const bf16x8*)(VT_ + ((row * 256 + ks * 64 + lg * 16) ^ ((row & 7) << 4)));
    }
    char* const PBw = PB_ + wv * 4096;
    const int pswz = (l15 & 7) << 4;

    // 2-stage pipeline: bias (global) + qf (LDS) prefetched one qt ahead.
    f32x4 biasE[8], biasO[8];
    bf16x8 qfE, qfO;
    ATT_LOADB(biasE, 0);
    ATT_LOADQ(qfE, 0);
    #pragma unroll
    for (int qq = 0; qq < 4; ++qq) {
      ATT_LOADB(biasO, 2 * qq + 1);
      ATT_LOADQ(qfO, 2 * qq + 1);
      ATT_BODY(2 * qq, biasE, qfE);
      if (qq < 3) {
        ATT_LOADB(biasE, 2 * qq + 2);
        ATT_LOADQ(qfE, 2 * qq + 2);
      }
      ATT_BODY(2 * qq + 1, biasO, qfO);
    }
  }
  __syncthreads();

  // ---- phase 4: proj^T (A = proj_w^T image, B = attn-out) + residual ----
  {
    bf16x8 pa2[2];
    #pragma unroll
    for (int ks = 0; ks < 2; ++ks)
      pa2[ks] = *(const bf16x8*)((const char*)projF + (((wv * 2 + ks)) << 10) + l * 16);
    const f32x4 bp = *(const f32x4*)(proj_b + wv * 16 + lg * 4);
    #pragma unroll
    for (int nt = 0; nt < 8; ++nt) {
      const int row = 16 * nt + l15;       // token
      const int rswz = (row & 7) << 4;
      bf16x8 t0 = *(const bf16x8*)(TOK_ + ((row * 128 +  0 + lg * 16) ^ rswz));
      bf16x8 t1 = *(const bf16x8*)(TOK_ + ((row * 128 + 64 + lg * 16) ^ rswz));
      f32x4 acc = bp;
      acc = __builtin_amdgcn_mfma_f32_16x16x32_bf16(pa2[0], t0, acc, 0, 0, 0);
      acc = __builtin_amdgcn_mfma_f32_16x16x32_bf16(pa2[1], t1, acc, 0, 0, 0);
      // D col=token(l15), row=4 consecutive out-ch -> dwordx4 residual
      int g = row & 63;
      long long base = ((long long)b * LL + (long long)(wh * GG + (g >> 3)) * W0c + (ww * GG + (g & 7))) * CC
                       + wv * 16 + lg * 4;
      const float* src = ((row & 64) ? y : x) + base;
      float* dst = out + ((row & 64) ? MODSZ : 0) + base;
      f32x4 sv = *(const f32x4*)src;
      sv[0] += acc[0]; sv[1] += acc[1]; sv[2] += acc[2]; sv[3] += acc[3];
      *(f32x4*)dst = sv;
    }
  }
}

// ---------------------------------------------------------------------------
// Kernel M v2: transposed-operand MFMA MLP (final)
// ---------------------------------------------------------------------------
__launch_bounds__(256, 3)
__global__ void mlp_mfma_kernel(const float* __restrict__ n2g, const float* __restrict__ n2b,
                                const float* __restrict__ fx1b, const float* __restrict__ fx2b,
                                const float* __restrict__ fy1b, const float* __restrict__ fy2b,
                                const short* __restrict__ mlpW, float* __restrict__ out) {
  __shared__ __align__(16) char AR4[4][8192];

  const int tid = threadIdx.x;
  const int l   = tid & 63;
  const int l15 = l & 15;
  const int lg  = l >> 4;
  const int wv  = tid >> 6;
  const int bid = blockIdx.x;
  const int mod = bid >> 10;                         // 0=x, 1=y
  const long long wtok0 = (long long)(bid & 1023) * 128 + wv * 32;

  const float* b1 = mod ? fy1b : fx1b;
  const float* b2 = mod ? fy2b : fx2b;
  const short* w1T = mlpW + mod * 16384;
  const short* w2T = mlpW + 32768 + mod * 16384;
  float* const outm = out + (long long)mod * MODSZ;

  char* const TOKw = AR4[wv];            // 32 rows, stride 144 B
  char* const HBw  = AR4[wv] + 4608;     // 32 rows, stride 80 B

  {
    const f32x4 g4 = *(const f32x4*)(n2g + l15 * 4);
    const f32x4 b4 = *(const f32x4*)(n2b + l15 * 4);
    #pragma unroll
    for (int ps = 0; ps < 8; ++ps) {
      int t = ps * 4 + lg;
      const float* rp = outm + (wtok0 + t) * CC + l15 * 4;
      f32x4 v = *(const f32x4*)rp;
      float s  = v[0] + v[1] + v[2] + v[3];
      float s2 = v[0] * v[0] + v[1] * v[1] + v[2] * v[2] + v[3] * v[3];
      #pragma unroll
      for (int m = 1; m < 16; m <<= 1) { s += __shfl_xor(s, m); s2 += __shfl_xor(s2, m); }
      float mu  = s * (1.0f / 64.0f);
      float var = fmaxf(s2 * (1.0f / 64.0f) - mu * mu, 0.0f);
      float rs  = rsqrtf(var + 1e-5f);
      bf16x4 w4 = mk4_bf16((v[0] - mu) * rs * g4[0] + b4[0],
                           (v[1] - mu) * rs * g4[1] + b4[1],
                           (v[2] - mu) * rs * g4[2] + b4[2],
                           (v[3] - mu) * rs * g4[3] + b4[3]);
      *(bf16x4*)(TOKw + t * 144 + l15 * 8) = w4;
    }
  }

  bf16x8 tokB[2][2];
  #pragma unroll
  for (int ct = 0; ct < 2; ++ct)
    #pragma unroll
    for (int ks = 0; ks < 2; ++ks)
      tokB[ct][ks] = *(const bf16x8*)(TOKw + (16 * ct + l15) * 144 + ks * 64 + lg * 16);

  f32x4 acc2[4][2];
  #pragma unroll
  for (int n = 0; n < 4; ++n) {
    f32x4 bb = *(const f32x4*)(b2 + n * 16 + lg * 4);
    acc2[n][0] = bb; acc2[n][1] = bb;
  }

  #pragma unroll 1
  for (int g2 = 0; g2 < 8; ++g2) {
    #pragma unroll
    for (int sub = 0; sub < 2; ++sub) {
      const int nt = g2 * 2 + sub;
      bf16x8 wa0 = *(const bf16x8*)(w1T + ((nt * 2 + 0) << 9) + l * 8);
      bf16x8 wa1 = *(const bf16x8*)(w1T + ((nt * 2 + 1) << 9) + l * 8);
      f32x4 z = {0.0f, 0.0f, 0.0f, 0.0f};
      f32x4 d0 = __builtin_amdgcn_mfma_f32_16x16x32_bf16(wa0, tokB[0][0], z, 0, 0, 0);
      d0 = __builtin_amdgcn_mfma_f32_16x16x32_bf16(wa1, tokB[0][1], d0, 0, 0, 0);
      f32x4 d1 = __builtin_amdgcn_mfma_f32_16x16x32_bf16(wa0, tokB[1][0], z, 0, 0, 0);
      d1 = __builtin_amdgcn_mfma_f32_16x16x32_bf16(wa1, tokB[1][1], d1, 0, 0, 0);
      f32x4 b1v = *(const f32x4*)(b1 + nt * 16 + lg * 4);
      bf16x4 h0 = mk4_bf16(gelu_tanh(d0[0] + b1v[0]), gelu_tanh(d0[1] + b1v[1]),
                           gelu_tanh(d0[2] + b1v[2]), gelu_tanh(d0[3] + b1v[3]));
      bf16x4 h1 = mk4_bf16(gelu_tanh(d1[0] + b1v[0]), gelu_tanh(d1[1] + b1v[1]),
                           gelu_tanh(d1[2] + b1v[2]), gelu_tanh(d1[3] + b1v[3]));
      *(bf16x4*)(HBw + l15 * 80        + sub * 32 + lg * 8) = h0;
      *(bf16x4*)(HBw + (16 + l15) * 80 + sub * 32 + lg * 8) = h1;
    }
    bf16x8 hb0 = *(const bf16x8*)(HBw + l15 * 80        + lg * 16);
    bf16x8 hb1 = *(const bf16x8*)(HBw + (16 + l15) * 80 + lg * 16);
    #pragma unroll
    for (int n = 0; n < 4; ++n) {
      bf16x8 wa = *(const bf16x8*)(w2T + ((n * 8 + g2) << 9) + l * 8);
      acc2[n][0] = __builtin_amdgcn_mfma_f32_16x16x32_bf16(wa, hb0, acc2[n][0], 0, 0, 0);
      acc2[n][1] = __builtin_amdgcn_mfma_f32_16x16x32_bf16(wa, hb1, acc2[n][1], 0, 0, 0);
    }
  }

  #pragma unroll
  for (int n = 0; n < 4; ++n)
    #pragma unroll
    for (int ct = 0; ct < 2; ++ct) {
      float* rp = outm + (wtok0 + 16 * ct + l15) * CC + n * 16 + lg * 4;
      f32x4 o = *(const f32x4*)rp;
      o[0] += acc2[n][ct][0]; o[1] += acc2[n][ct][1];
      o[2] += acc2[n][ct][2]; o[3] += acc2[n][ct][3];
      *(f32x4*)rp = o;
    }
}

// ---------------------------------------------------------------------------
extern "C" void kernel_launch(void* const* d_in, const int* in_sizes, int n_in,
                              void* d_out, int out_size, void* d_ws, size_t ws_size,
                              hipStream_t stream) {
  const float* x      = (const float*)d_in[0];
  const float* y      = (const float*)d_in[1];
  const float* n1g    = (const float*)d_in[2];
  const float* n1b    = (const float*)d_in[3];
  const float* qkv_w  = (const float*)d_in[4];
  const float* qkv_b  = (const float*)d_in[5];
  const float* proj_w = (const float*)d_in[6];
  const float* proj_b = (const float*)d_in[7];
  const float* pp_w   = (const float*)d_in[8];
  const float* pp_b   = (const float*)d_in[9];
  const float* ln1g   = (const float*)d_in[10];
  const float* ln1b   = (const float*)d_in[11];
  const float* l1w    = (const float*)d_in[12];
  const float* l1b    = (const float*)d_in[13];
  const float* ln2g   = (const float*)d_in[14];
  const float* ln2b   = (const float*)d_in[15];
  const float* l2w    = (const float*)d_in[16];
  const float* l2b    = (const float*)d_in[17];
  const float* ln3g   = (const float*)d_in[18];
  const float* ln3b   = (const float*)d_in[19];
  const float* l3w    = (const float*)d_in[20];
  const float* l3b    = (const float*)d_in[21];
  const float* n2g    = (const float*)d_in[22];
  const float* n2b    = (const float*)d_in[23];
  const float* fx1w   = (const float*)d_in[24];
  const float* fx1b   = (const float*)d_in[25];
  const float* fx2w   = (const float*)d_in[26];
  const float* fx2b   = (const float*)d_in[27];
  const float* fy1w   = (const float*)d_in[28];
  const float* fy1b   = (const float*)d_in[29];
  const float* fy2w   = (const float*)d_in[30];
  const float* fy2b   = (const float*)d_in[31];
  (void)in_sizes; (void)n_in; (void)out_size; (void)ws_size;

  float* out = (float*)d_out;
  char*  ws  = (char*)d_ws;
  float* p_table  = (float*)(ws + WS_PTAB);
  float* bias_exp = (float*)(ws + WS_BIAS);
  short* wqkvF    = (short*)(ws + WS_WQKV);
  short* projF    = (short*)(ws + WS_WPROJ);
  short* mlpW     = (short*)(ws + WS_MLPW);

  pbias_kernel<<<1, 512, 0, stream>>>(pp_w, pp_b, ln1g, ln1b, l1w, l1b,
                                      ln2g, ln2b, l2w, l2b, ln3g, ln3b, l3w, l3b, p_table);
  bias_expand_kernel<<<64, 256, 0, stream>>>(p_table, bias_exp);
  prep_w_kernel<<<64, 256, 0, stream>>>(qkv_w, proj_w, wqkvF, projF);
  prep_mlp_w_kernel<<<256, 256, 0, stream>>>(fx1w, fy1w, fx2w, fy2w, mlpW);
  win_attn_kernel<<<NWIN, 256, 0, stream>>>(x, y, n1g, n1b, qkv_b, proj_b,
                                            bias_exp, wqkvF, projF, out);
  mlp_mfma_kernel<<<2048, 256, 0, stream>>>(n2g, n2b, fx1b, fx2b, fy1b, fy2b,
                                            mlpW, out);
}

// Round 17
// 155.425 us; speedup vs baseline: 1.1346x; 1.0876x over previous
//
#include <hip/hip_runtime.h>
#include <math.h>

constexpr int CC    = 64;          // channels
constexpr int GG    = 8;           // window size
constexpr int H0    = 256;
constexpr int W0c   = 256;
constexpr int BB    = 2;
constexpr int LL    = H0 * W0c;                     // 65536
constexpr int NWIN  = BB * (H0 / GG) * (W0c / GG);  // 2048
constexpr int HIDN  = 256;                          // MLP hidden
constexpr int NBIA  = 31 * 15;                      // 465 relative-pos entries
constexpr long long MODSZ = (long long)BB * LL * CC; // 8388608 floats per modality

constexpr float INV_LN2 = 1.4426950408889634f;

// ws byte offsets
constexpr int WS_PTAB  = 0;        // 465*4 f32
constexpr int WS_BIAS  = 8192;     // [4][128][128] f32 = 256 KB (pre-scaled by 1/ln2)
constexpr int WS_WQKV  = 270336;   // 24 slots * 512 bf16 = 24 KB (frag image)
constexpr int WS_WPROJ = 294912;   // 8 slots * 512 bf16 = 8 KB
constexpr int WS_MLPW  = 303104;   // 4 images * 16384 bf16 = 128 KB (A-frag images)

using f32x4  = __attribute__((ext_vector_type(4))) float;
using bf16x8 = __attribute__((ext_vector_type(8))) short;
using bf16x4 = __attribute__((ext_vector_type(4))) short;

static __device__ __forceinline__ short to_bf16(float f) {   // RNE (prep kernels)
  unsigned u = __float_as_uint(f);
  unsigned r = (u + 0x7FFFu + ((u >> 16) & 1u)) >> 16;
  return (short)r;
}
// hot-path packing: round-half-up, pair-packed in pure C (no asm — round-5 lesson)
static __device__ __forceinline__ bf16x4 mk4_bf16(float a, float b, float c, float d) {
  unsigned p0 = ((__float_as_uint(a) + 0x8000u) >> 16) | ((__float_as_uint(b) + 0x8000u) & 0xFFFF0000u);
  unsigned p1 = ((__float_as_uint(c) + 0x8000u) >> 16) | ((__float_as_uint(d) + 0x8000u) & 0xFFFF0000u);
  bf16x4 r;
  r[0] = (short)(p0 & 0xFFFFu); r[1] = (short)(p0 >> 16);
  r[2] = (short)(p1 & 0xFFFFu); r[3] = (short)(p1 >> 16);
  return r;
}
static __device__ __forceinline__ float gelu_tanh(float u) {
  float u2 = u * u;
  float t  = fmaf(0.044715f, u2, 1.0f);
  float z  = u * t * 1.5957691216057308f;
  float e  = __expf(-z);
  return u / (1.0f + e);
}

// ---------------------------------------------------------------------------
// Kernel P: dynamic position bias table (465 x 4) via tiny MLP
// ---------------------------------------------------------------------------
static __device__ __forceinline__ void ln4_relu(float* p, const float* g, const float* b) {
  float mu = 0.25f * (p[0] + p[1] + p[2] + p[3]);
  float d0 = p[0] - mu, d1 = p[1] - mu, d2 = p[2] - mu, d3 = p[3] - mu;
  float var = 0.25f * (d0 * d0 + d1 * d1 + d2 * d2 + d3 * d3);
  float rs = rsqrtf(var + 1e-5f);
  p[0] = fmaxf(d0 * rs * g[0] + b[0], 0.0f);
  p[1] = fmaxf(d1 * rs * g[1] + b[1], 0.0f);
  p[2] = fmaxf(d2 * rs * g[2] + b[2], 0.0f);
  p[3] = fmaxf(d3 * rs * g[3] + b[3], 0.0f);
}
static __device__ __forceinline__ void mm4(const float* a, const float* w, const float* b, float* o) {
  #pragma unroll
  for (int j = 0; j < 4; ++j) {
    float s = b[j];
    #pragma unroll
    for (int i = 0; i < 4; ++i) s += a[i] * w[i * 4 + j];
    o[j] = s;
  }
}

__global__ void pbias_kernel(const float* __restrict__ pp_w, const float* __restrict__ pp_b,
                             const float* __restrict__ ln1g, const float* __restrict__ ln1b,
                             const float* __restrict__ l1w,  const float* __restrict__ l1b,
                             const float* __restrict__ ln2g, const float* __restrict__ ln2b,
                             const float* __restrict__ l2w,  const float* __restrict__ l2b,
                             const float* __restrict__ ln3g, const float* __restrict__ ln3b,
                             const float* __restrict__ l3w,  const float* __restrict__ l3b,
                             float* __restrict__ p_table) {
  int r = blockIdx.x * blockDim.x + threadIdx.x;
  if (r >= NBIA) return;
  float bh = (float)(r / 15 - 15);
  float bw = (float)(r % 15 - 7);
  float a[4], t[4];
  #pragma unroll
  for (int j = 0; j < 4; ++j) a[j] = bh * pp_w[j] + bw * pp_w[4 + j] + pp_b[j];
  ln4_relu(a, ln1g, ln1b);
  mm4(a, l1w, l1b, t);
  ln4_relu(t, ln2g, ln2b);
  mm4(t, l2w, l2b, a);
  ln4_relu(a, ln3g, ln3b);
  mm4(a, l3w, l3b, t);
  #pragma unroll
  for (int j = 0; j < 4; ++j) p_table[r * 4 + j] = t[j];
}

// ---------------------------------------------------------------------------
// bias_expand: p_table (465x4) -> dense bias_exp[h][q][k] f32, PRE-SCALED by
// 1/ln2 so the kernel's softmax is a single v_exp (exp2) per score.
// ---------------------------------------------------------------------------
__global__ void bias_expand_kernel(const float* __restrict__ p_table, float* __restrict__ bias_exp) {
  int gid = blockIdx.x * 256 + threadIdx.x;   // 16384 float4's
  int h   = gid >> 12;
  int rem = gid & 4095;
  int q   = rem >> 5;
  int k0  = (rem & 31) * 4;
  int qih = q >> 3, qiw = q & 7;
  float o[4];
  #pragma unroll
  for (int kk = 0; kk < 4; ++kk) {
    int k = k0 + kk;
    int ridx = (qih - (k >> 3) + 15) * 15 + (qiw - (k & 7) + 7);
    o[kk] = p_table[ridx * 4 + h] * INV_LN2;
  }
  f32x4 v = {o[0], o[1], o[2], o[3]};
  *(f32x4*)(bias_exp + gid * 4) = v;
}

// ---------------------------------------------------------------------------
// prep_w: weight frag images (unchanged; q-scale * 1/ln2 folded)
// ---------------------------------------------------------------------------
__global__ void prep_w_kernel(const float* __restrict__ qkv_w, const float* __restrict__ proj_w,
                              short* __restrict__ wqkvF, short* __restrict__ projF) {
  int t = blockIdx.x * 256 + threadIdx.x;    // 16384
  if (t < 12288) {
    int slot = t >> 9, e = t & 511;
    int lp = e >> 3, j = e & 7;
    int ng = slot >> 1, s = slot & 1;
    int k   = 32 * s + 8 * (lp >> 4) + j;
    int col = 16 * ng + (lp & 15);
    float v = qkv_w[k * 192 + col];
    if (col < 64) v *= 0.25f * INV_LN2;
    wqkvF[t] = to_bf16(v);
  } else {
    int t2 = t - 12288;
    int slot = t2 >> 9, e = t2 & 511;
    int lp = e >> 3, j = e & 7;
    int ng = slot >> 1, s = slot & 1;
    int k   = 32 * s + 8 * (lp >> 4) + j;
    int col = 16 * ng + (lp & 15);
    projF[t2] = to_bf16(proj_w[k * 64 + col]);
  }
}

// ---------------------------------------------------------------------------
// prep_mlp_w (unchanged)
// ---------------------------------------------------------------------------
__global__ void prep_mlp_w_kernel(const float* __restrict__ fx1w, const float* __restrict__ fy1w,
                                  const float* __restrict__ fx2w, const float* __restrict__ fy2w,
                                  short* __restrict__ mlpW) {
  int gid = blockIdx.x * 256 + threadIdx.x;   // 65536
  int img = gid >> 14;
  int e   = gid & 16383;
  int slot = e >> 9, lp = (e >> 3) & 63, j = e & 7;
  float v;
  if (img < 2) {
    const float* w1 = img ? fy1w : fx1w;      // (64 x 256)
    int nt = slot >> 1, ks = slot & 1;
    int in_ch = ks * 32 + ((lp >> 4) << 3) + j;
    int hid   = nt * 16 + (lp & 15);
    v = w1[in_ch * HIDN + hid];
  } else {
    const float* w2 = (img & 1) ? fy2w : fx2w; // (256 x 64)
    int nt2 = slot >> 3, g2 = slot & 7;
    int hid = g2 * 32 + ((lp >> 4) << 3) + j;
    int oc  = nt2 * 16 + (lp & 15);
    v = w2[hid * CC + oc];
  }
  mlpW[gid] = to_bf16(v);
}

// ---------------------------------------------------------------------------
// Kernel FUSED: round-9 attention (phases 1-4, proven) + MLP (phase 5, the
// proven mlp_mfma pipeline) with a 32 KB f32 LDS handoff (TOKF).
// LDS map: TOK 0..16K | QB/KB 16K..48K (phase2-3; TOKF overlays after) |
//          VT 48K..64K, PB 64K..80K (phase2-3; MARENA overlays in phase 5).
// TOKF quad-XOR swizzle: byteoff = (ch*4) ^ ((row&7)<<4).
// ---------------------------------------------------------------------------

#define ATT_LOADB(biasreg, qt) { \
  _Pragma("unroll") \
  for (int kt_ = 0; kt_ < 8; ++kt_) \
    biasreg[kt_] = *(const f32x4*)(biasH + (16 * (qt) + l15) * 128 + 16 * kt_ + 4 * lg); }

#define ATT_LOADQ(qfreg, qt) { \
  qfreg = (bf16x8){0, 0, 0, 0, 0, 0, 0, 0}; \
  if (l < 32) { \
    int row_ = 16 * (qt) + l15; \
    qfreg = *(const bf16x8*)(QB_ + ((row_ * 128 + h * 32 + lg * 16) ^ ((row_ & 7) << 4))); } }

#define ATT_BODY(qt, biasreg, qfreg) { \
  f32x4 s_[8]; \
  _Pragma("unroll") \
  for (int kt_ = 0; kt_ < 8; ++kt_) \
    s_[kt_] = __builtin_amdgcn_mfma_f32_16x16x32_bf16(kf[kt_], qfreg, biasreg[kt_], 0, 0, 0); \
  float sum_ = 0.0f; \
  _Pragma("unroll") \
  for (int kt_ = 0; kt_ < 8; ++kt_) { \
    s_[kt_][0] = __builtin_amdgcn_exp2f(s_[kt_][0]); \
    s_[kt_][1] = __builtin_amdgcn_exp2f(s_[kt_][1]); \
    s_[kt_][2] = __builtin_amdgcn_exp2f(s_[kt_][2]); \
    s_[kt_][3] = __builtin_amdgcn_exp2f(s_[kt_][3]); \
    sum_ += (s_[kt_][0] + s_[kt_][1]) + (s_[kt_][2] + s_[kt_][3]); } \
  sum_ += __shfl_xor(sum_, 16); \
  sum_ += __shfl_xor(sum_, 32); \
  float inv_ = 1.0f / sum_; \
  _Pragma("unroll") \
  for (int kt_ = 0; kt_ < 8; ++kt_) { \
    int k0_ = 16 * kt_ + 4 * lg; \
    *(bf16x4*)(PBw + ((l15 * 256 + k0_ * 2) ^ pswz)) = mk4_bf16(s_[kt_][0], s_[kt_][1], s_[kt_][2], s_[kt_][3]); } \
  f32x4 pacc_ = {0.0f, 0.0f, 0.0f, 0.0f}; \
  _Pragma("unroll") \
  for (int ks_ = 0; ks_ < 4; ++ks_) { \
    bf16x8 pa_ = *(const bf16x8*)(PBw + ((l15 * 256 + ks_ * 64 + lg * 16) ^ pswz)); \
    pacc_ = __builtin_amdgcn_mfma_f32_16x16x32_bf16(vf[ks_], pa_, pacc_, 0, 0, 0); } \
  pacc_[0] *= inv_; pacc_[1] *= inv_; pacc_[2] *= inv_; pacc_[3] *= inv_; \
  *(bf16x4*)(TOK_ + (((16 * (qt) + l15) * 128 + (h * 16 + lg * 4) * 2) ^ (((16 * (qt) + l15) & 7) << 4))) \
      = mk4_bf16(pacc_[0], pacc_[1], pacc_[2], pacc_[3]); }

__launch_bounds__(256, 2)
__global__ void fused_kernel(const float* __restrict__ x, const float* __restrict__ y,
                             const float* __restrict__ n1g, const float* __restrict__ n1b,
                             const float* __restrict__ qkv_b, const float* __restrict__ proj_b,
                             const float* __restrict__ bias_exp,
                             const short* __restrict__ wqkvF, const short* __restrict__ projF,
                             const float* __restrict__ n2g, const float* __restrict__ n2b,
                             const float* __restrict__ fx1b, const float* __restrict__ fx2b,
                             const float* __restrict__ fy1b, const float* __restrict__ fy2b,
                             const short* __restrict__ mlpW,
                             float* __restrict__ out) {
  __shared__ __align__(16) char smem[81920];
  char* const TOK_  = smem;            // 16 KB [128 tok][64 ch] bf16 (LN'd; later attn-out)
  char* const QB_   = smem + 16384;    // 16 KB (phases 2-3)
  char* const KB_   = smem + 32768;    // 16 KB (phases 2-3)
  char* const VT_   = smem + 49152;    // 16 KB (phases 2-3)
  char* const PB_   = smem + 65536;    // 16 KB (phase 3)
  char* const TOKF_ = smem + 16384;    // 32 KB f32 [128 tok][64 ch] (phase 4-5, over QB/KB)
  char* const MAR_  = smem + 49152;    // 32 KB MLP arenas (phase 5, over VT/PB)

  const int tid = threadIdx.x;
  const int l   = tid & 63;
  const int l15 = l & 15;
  const int lg  = l >> 4;
  const int wv  = __builtin_amdgcn_readfirstlane(tid >> 6);

  const int widx = blockIdx.x;
  const int b  = widx >> 10;
  const int wl = widx & 1023;
  const int wh = wl >> 5, ww = wl & 31;

  // ---- phase 1: gather + LN(norm1) -> bf16 token tile (row-swizzled) ----
  {
    const int lane16 = tid & 15;
    const float4 g4 = *(const float4*)(n1g + lane16 * 4);
    const float4 b4 = *(const float4*)(n1b + lane16 * 4);
    #pragma unroll
    for (int ps = 0; ps < 8; ++ps) {
      int t  = ps * 16 + (tid >> 4);
      int g  = t & 63;
      const float* src = ((t & 64) ? y : x)
          + ((long long)b * LL + (long long)(wh * GG + (g >> 3)) * W0c + (ww * GG + (g & 7))) * CC
          + lane16 * 4;
      float4 v = *(const float4*)src;
      float s  = v.x + v.y + v.z + v.w;
      float s2 = v.x * v.x + v.y * v.y + v.z * v.z + v.w * v.w;
      #pragma unroll
      for (int m = 1; m < 16; m <<= 1) { s += __shfl_xor(s, m); s2 += __shfl_xor(s2, m); }
      float mu  = s * (1.0f / 64.0f);
      float var = fmaxf(s2 * (1.0f / 64.0f) - mu * mu, 0.0f);
      float rs  = rsqrtf(var + 1e-5f);
      bf16x4 w4 = mk4_bf16((v.x - mu) * rs * g4.x + b4.x,
                           (v.y - mu) * rs * g4.y + b4.y,
                           (v.z - mu) * rs * g4.z + b4.z,
                           (v.w - mu) * rs * g4.w + b4.w);
      *(bf16x4*)(TOK_ + ((t * 128 + lane16 * 8) ^ ((t & 7) << 4))) = w4;
    }
  }
  __syncthreads();

  // ---- phase 2: QKV (waves 0,1 -> Q^T; waves 2,3 -> K^T; all -> one V tile) ----
  {
    bf16x8 awq[2][2];
    #pragma unroll
    for (int ct = 0; ct < 2; ++ct)
      #pragma unroll
      for (int ks = 0; ks < 2; ++ks)
        awq[ct][ks] = *(const bf16x8*)((const char*)wqkvF + ((((2 * wv + ct) * 2 + ks)) << 10) + l * 16);
    bf16x8 bwv[2];
    #pragma unroll
    for (int ks = 0; ks < 2; ++ks)
      bwv[ks] = *(const bf16x8*)((const char*)wqkvF + (((8 + wv) * 2 + ks) << 10) + l * 16);

    f32x4 bq[2];
    #pragma unroll
    for (int ct = 0; ct < 2; ++ct) {
      f32x4 bb = *(const f32x4*)(qkv_b + (2 * wv + ct) * 16 + lg * 4);
      if (wv < 2) {
        const float qs = 0.25f * INV_LN2;
        bb[0] *= qs; bb[1] *= qs; bb[2] *= qs; bb[3] *= qs;
      }
      bq[ct] = bb;
    }
    const float bv = qkv_b[128 + wv * 16 + l15];
    char* const QKbuf = (wv < 2) ? QB_ : KB_;
    const int chv = wv * 16 + l15;
    const int vswz = (chv & 7) << 4;

    #pragma unroll
    for (int nt = 0; nt < 8; ++nt) {
      const int row = 16 * nt + l15;
      const int rswz = (row & 7) << 4;
      bf16x8 t0 = *(const bf16x8*)(TOK_ + ((row * 128 +  0 + lg * 16) ^ rswz));
      bf16x8 t1 = *(const bf16x8*)(TOK_ + ((row * 128 + 64 + lg * 16) ^ rswz));
      #pragma unroll
      for (int ct = 0; ct < 2; ++ct) {
        f32x4 a = bq[ct];
        a = __builtin_amdgcn_mfma_f32_16x16x32_bf16(awq[ct][0], t0, a, 0, 0, 0);
        a = __builtin_amdgcn_mfma_f32_16x16x32_bf16(awq[ct][1], t1, a, 0, 0, 0);
        int chL = (((2 * wv + ct) * 16) & 63) + lg * 4;
        *(bf16x4*)(QKbuf + ((row * 128 + chL * 2) ^ rswz)) = mk4_bf16(a[0], a[1], a[2], a[3]);
      }
      {
        f32x4 a = {bv, bv, bv, bv};
        a = __builtin_amdgcn_mfma_f32_16x16x32_bf16(t0, bwv[0], a, 0, 0, 0);
        a = __builtin_amdgcn_mfma_f32_16x16x32_bf16(t1, bwv[1], a, 0, 0, 0);
        int tok0 = 16 * nt + lg * 4;
        *(bf16x4*)(VT_ + ((chv * 256 + tok0 * 2) ^ vswz)) = mk4_bf16(a[0], a[1], a[2], a[3]);
      }
    }
  }
  __syncthreads();

  // ---- phase 3: attention, wave = head.  S^T = K x Q (swapped). ----
  {
    const int h = wv;
    const float* biasH = bias_exp + h * 16384;
    bf16x8 kf[8];
    #pragma unroll
    for (int kt = 0; kt < 8; ++kt) {
      bf16x8 f = {0, 0, 0, 0, 0, 0, 0, 0};
      if (l < 32) {
        int row = 16 * kt + l15;
        f = *(const bf16x8*)(KB_ + ((row * 128 + h * 32 + lg * 16) ^ ((row & 7) << 4)));
      }
      kf[kt] = f;
    }
    bf16x8 vf[4];
    #pragma unroll
    for (int ks = 0; ks < 4; ++ks) {
      int row = h * 16 + l15;
      vf[ks] = *(const bf16x8*)(VT_ + ((row * 256 + ks * 64 + lg * 16) ^ ((row & 7) << 4)));
    }
    char* const PBw = PB_ + wv * 4096;
    const int pswz = (l15 & 7) << 4;

    f32x4 biasE[8], biasO[8];
    bf16x8 qfE, qfO;
    ATT_LOADB(biasE, 0);
    ATT_LOADQ(qfE, 0);
    #pragma unroll
    for (int qq = 0; qq < 4; ++qq) {
      ATT_LOADB(biasO, 2 * qq + 1);
      ATT_LOADQ(qfO, 2 * qq + 1);
      ATT_BODY(2 * qq, biasE, qfE);
      if (qq < 3) {
        ATT_LOADB(biasE, 2 * qq + 2);
        ATT_LOADQ(qfE, 2 * qq + 2);
      }
      ATT_BODY(2 * qq + 1, biasO, qfO);
    }
  }
  __syncthreads();   // attn-out complete in TOK_; QB/KB/VT/PB now dead

  // ---- phase 4: proj^T + residual -> TOKF (f32, LDS) ----
  {
    bf16x8 pa2[2];
    #pragma unroll
    for (int ks = 0; ks < 2; ++ks)
      pa2[ks] = *(const bf16x8*)((const char*)projF + (((wv * 2 + ks)) << 10) + l * 16);
    const f32x4 bp = *(const f32x4*)(proj_b + wv * 16 + lg * 4);
    #pragma unroll
    for (int nt = 0; nt < 8; ++nt) {
      const int row = 16 * nt + l15;       // token
      const int rswz = (row & 7) << 4;
      bf16x8 t0 = *(const bf16x8*)(TOK_ + ((row * 128 +  0 + lg * 16) ^ rswz));
      bf16x8 t1 = *(const bf16x8*)(TOK_ + ((row * 128 + 64 + lg * 16) ^ rswz));
      f32x4 acc = bp;
      acc = __builtin_amdgcn_mfma_f32_16x16x32_bf16(pa2[0], t0, acc, 0, 0, 0);
      acc = __builtin_amdgcn_mfma_f32_16x16x32_bf16(pa2[1], t1, acc, 0, 0, 0);
      int g = row & 63;
      long long base = ((long long)b * LL + (long long)(wh * GG + (g >> 3)) * W0c + (ww * GG + (g & 7))) * CC
                       + wv * 16 + lg * 4;
      const float* src = ((row & 64) ? y : x) + base;
      f32x4 sv = *(const f32x4*)src;
      sv[0] += acc[0]; sv[1] += acc[1]; sv[2] += acc[2]; sv[3] += acc[3];
      // store residual row to TOKF (quad-XOR swizzle); ch = wv*16+lg*4
      *(f32x4*)(TOKF_ + row * 256 + (((wv * 64 + lg * 16)) ^ rswz)) = sv;
    }
  }
  __syncthreads();   // TOKF complete (all channels from all waves)

  // ---- phase 5: fused MLP.  Wave wv owns tokens [32wv, 32wv+32); modality
  //      mod = wv>=2.  Exact mlp_mfma pipeline, LN input from TOKF. ----
  {
    const int mod = wv >> 1;
    const float* b1 = mod ? fy1b : fx1b;
    const float* b2 = mod ? fy2b : fx2b;
    const short* w1T = mlpW + mod * 16384;
    const short* w2T = mlpW + 32768 + mod * 16384;
    char* const TOKw = MAR_ + wv * 8192;       // 32 rows, stride 144 B
    char* const HBw  = TOKw + 4608;            // 32 rows, stride 80 B

    // LN(norm2): 8 ps x 4 tokens (lg), 16 lanes/token (l15), 4 ch each
    {
      const f32x4 g4 = *(const f32x4*)(n2g + l15 * 4);
      const f32x4 b4 = *(const f32x4*)(n2b + l15 * 4);
      #pragma unroll
      for (int ps = 0; ps < 8; ++ps) {
        int t   = ps * 4 + lg;                 // local 0..31
        int row = wv * 32 + t;                 // window token
        f32x4 v = *(const f32x4*)(TOKF_ + row * 256 + ((l15 * 16) ^ ((row & 7) << 4)));
        float s  = v[0] + v[1] + v[2] + v[3];
        float s2 = v[0] * v[0] + v[1] * v[1] + v[2] * v[2] + v[3] * v[3];
        #pragma unroll
        for (int m = 1; m < 16; m <<= 1) { s += __shfl_xor(s, m); s2 += __shfl_xor(s2, m); }
        float mu  = s * (1.0f / 64.0f);
        float var = fmaxf(s2 * (1.0f / 64.0f) - mu * mu, 0.0f);
        float rs  = rsqrtf(var + 1e-5f);
        bf16x4 w4 = mk4_bf16((v[0] - mu) * rs * g4[0] + b4[0],
                             (v[1] - mu) * rs * g4[1] + b4[1],
                             (v[2] - mu) * rs * g4[2] + b4[2],
                             (v[3] - mu) * rs * g4[3] + b4[3]);
        *(bf16x4*)(TOKw + t * 144 + l15 * 8) = w4;
      }
    }
    // per-wave-private arenas: no block barrier needed inside phase 5.

    bf16x8 tokB[2][2];
    #pragma unroll
    for (int ct = 0; ct < 2; ++ct)
      #pragma unroll
      for (int ks = 0; ks < 2; ++ks)
        tokB[ct][ks] = *(const bf16x8*)(TOKw + (16 * ct + l15) * 144 + ks * 64 + lg * 16);

    f32x4 acc2[4][2];
    #pragma unroll
    for (int n = 0; n < 4; ++n) {
      f32x4 bb = *(const f32x4*)(b2 + n * 16 + lg * 4);
      acc2[n][0] = bb; acc2[n][1] = bb;
    }

    #pragma unroll 1
    for (int g2 = 0; g2 < 8; ++g2) {
      #pragma unroll
      for (int sub = 0; sub < 2; ++sub) {
        const int nt = g2 * 2 + sub;
        bf16x8 wa0 = *(const bf16x8*)(w1T + ((nt * 2 + 0) << 9) + l * 8);
        bf16x8 wa1 = *(const bf16x8*)(w1T + ((nt * 2 + 1) << 9) + l * 8);
        f32x4 z = {0.0f, 0.0f, 0.0f, 0.0f};
        f32x4 d0 = __builtin_amdgcn_mfma_f32_16x16x32_bf16(wa0, tokB[0][0], z, 0, 0, 0);
        d0 = __builtin_amdgcn_mfma_f32_16x16x32_bf16(wa1, tokB[0][1], d0, 0, 0, 0);
        f32x4 d1 = __builtin_amdgcn_mfma_f32_16x16x32_bf16(wa0, tokB[1][0], z, 0, 0, 0);
        d1 = __builtin_amdgcn_mfma_f32_16x16x32_bf16(wa1, tokB[1][1], d1, 0, 0, 0);
        f32x4 b1v = *(const f32x4*)(b1 + nt * 16 + lg * 4);
        bf16x4 h0 = mk4_bf16(gelu_tanh(d0[0] + b1v[0]), gelu_tanh(d0[1] + b1v[1]),
                             gelu_tanh(d0[2] + b1v[2]), gelu_tanh(d0[3] + b1v[3]));
        bf16x4 h1 = mk4_bf16(gelu_tanh(d1[0] + b1v[0]), gelu_tanh(d1[1] + b1v[1]),
                             gelu_tanh(d1[2] + b1v[2]), gelu_tanh(d1[3] + b1v[3]));
        *(bf16x4*)(HBw + l15 * 80        + sub * 32 + lg * 8) = h0;
        *(bf16x4*)(HBw + (16 + l15) * 80 + sub * 32 + lg * 8) = h1;
      }
      bf16x8 hb0 = *(const bf16x8*)(HBw + l15 * 80        + lg * 16);
      bf16x8 hb1 = *(const bf16x8*)(HBw + (16 + l15) * 80 + lg * 16);
      #pragma unroll
      for (int n = 0; n < 4; ++n) {
        bf16x8 wa = *(const bf16x8*)(w2T + ((n * 8 + g2) << 9) + l * 8);
        acc2[n][0] = __builtin_amdgcn_mfma_f32_16x16x32_bf16(wa, hb0, acc2[n][0], 0, 0, 0);
        acc2[n][1] = __builtin_amdgcn_mfma_f32_16x16x32_bf16(wa, hb1, acc2[n][1], 0, 0, 0);
      }
    }

    // epilogue: resid (TOKF) + mlp_out -> final scatter store to out
    #pragma unroll
    for (int n = 0; n < 4; ++n)
      #pragma unroll
      for (int ct = 0; ct < 2; ++ct) {
        int row = wv * 32 + 16 * ct + l15;     // window token
        int ch  = n * 16 + lg * 4;
        f32x4 r = *(const f32x4*)(TOKF_ + row * 256 + ((ch * 4) ^ ((row & 7) << 4)));
        r[0] += acc2[n][ct][0]; r[1] += acc2[n][ct][1];
        r[2] += acc2[n][ct][2]; r[3] += acc2[n][ct][3];
        int g = row & 63;
        long long base = ((long long)b * LL + (long long)(wh * GG + (g >> 3)) * W0c + (ww * GG + (g & 7))) * CC + ch;
        float* dst = out + ((row & 64) ? MODSZ : 0) + base;
        *(f32x4*)dst = r;
      }
  }
}

// ---------------------------------------------------------------------------
extern "C" void kernel_launch(void* const* d_in, const int* in_sizes, int n_in,
                              void* d_out, int out_size, void* d_ws, size_t ws_size,
                              hipStream_t stream) {
  const float* x      = (const float*)d_in[0];
  const float* y      = (const float*)d_in[1];
  const float* n1g    = (const float*)d_in[2];
  const float* n1b    = (const float*)d_in[3];
  const float* qkv_w  = (const float*)d_in[4];
  const float* qkv_b  = (const float*)d_in[5];
  const float* proj_w = (const float*)d_in[6];
  const float* proj_b = (const float*)d_in[7];
  const float* pp_w   = (const float*)d_in[8];
  const float* pp_b   = (const float*)d_in[9];
  const float* ln1g   = (const float*)d_in[10];
  const float* ln1b   = (const float*)d_in[11];
  const float* l1w    = (const float*)d_in[12];
  const float* l1b    = (const float*)d_in[13];
  const float* ln2g   = (const float*)d_in[14];
  const float* ln2b   = (const float*)d_in[15];
  const float* l2w    = (const float*)d_in[16];
  const float* l2b    = (const float*)d_in[17];
  const float* ln3g   = (const float*)d_in[18];
  const float* ln3b   = (const float*)d_in[19];
  const float* l3w    = (const float*)d_in[20];
  const float* l3b    = (const float*)d_in[21];
  const float* n2g    = (const float*)d_in[22];
  const float* n2b    = (const float*)d_in[23];
  const float* fx1w   = (const float*)d_in[24];
  const float* fx1b   = (const float*)d_in[25];
  const float* fx2w   = (const float*)d_in[26];
  const float* fx2b   = (const float*)d_in[27];
  const float* fy1w   = (const float*)d_in[28];
  const float* fy1b   = (const float*)d_in[29];
  const float* fy2w   = (const float*)d_in[30];
  const float* fy2b   = (const float*)d_in[31];
  (void)in_sizes; (void)n_in; (void)out_size; (void)ws_size;

  float* out = (float*)d_out;
  char*  ws  = (char*)d_ws;
  float* p_table  = (float*)(ws + WS_PTAB);
  float* bias_exp = (float*)(ws + WS_BIAS);
  short* wqkvF    = (short*)(ws + WS_WQKV);
  short* projF    = (short*)(ws + WS_WPROJ);
  short* mlpW     = (short*)(ws + WS_MLPW);

  pbias_kernel<<<1, 512, 0, stream>>>(pp_w, pp_b, ln1g, ln1b, l1w, l1b,
                                      ln2g, ln2b, l2w, l2b, ln3g, ln3b, l3w, l3b, p_table);
  bias_expand_kernel<<<64, 256, 0, stream>>>(p_table, bias_exp);
  prep_w_kernel<<<64, 256, 0, stream>>>(qkv_w, proj_w, wqkvF, projF);
  prep_mlp_w_kernel<<<256, 256, 0, stream>>>(fx1w, fy1w, fx2w, fy2w, mlpW);
  fused_kernel<<<NWIN, 256, 0, stream>>>(x, y, n1g, n1b, qkv_b, proj_b,
                                         bias_exp, wqkvF, projF,
                                         n2g, n2b, fx1b, fx2b, fy1b, fy2b, mlpW, out);
}

// Round 18
// 153.086 us; speedup vs baseline: 1.1519x; 1.0153x over previous
//
#include <hip/hip_runtime.h>
#include <math.h>

constexpr int CC    = 64;          // channels
constexpr int GG    = 8;           // window size
constexpr int H0    = 256;
constexpr int W0c   = 256;
constexpr int BB    = 2;
constexpr int LL    = H0 * W0c;                     // 65536
constexpr int NWIN  = BB * (H0 / GG) * (W0c / GG);  // 2048
constexpr int HIDN  = 256;                          // MLP hidden
constexpr int NBIA  = 31 * 15;                      // 465 relative-pos entries
constexpr long long MODSZ = (long long)BB * LL * CC; // 8388608 floats per modality

constexpr float INV_LN2 = 1.4426950408889634f;

// ws byte offsets
constexpr int WS_PTAB  = 0;        // 465*4 f32
constexpr int WS_BIAS  = 8192;     // [4][128][128] f32 = 256 KB (pre-scaled by 1/ln2)
constexpr int WS_WQKV  = 270336;   // 24 slots * 512 bf16 = 24 KB (frag image)
constexpr int WS_WPROJ = 294912;   // 8 slots * 512 bf16 = 8 KB
constexpr int WS_MLPW  = 303104;   // 4 images * 16384 bf16 = 128 KB (A-frag images)

using f32x4  = __attribute__((ext_vector_type(4))) float;
using bf16x8 = __attribute__((ext_vector_type(8))) short;
using bf16x4 = __attribute__((ext_vector_type(4))) short;

static __device__ __forceinline__ short to_bf16(float f) {   // RNE (prep kernels)
  unsigned u = __float_as_uint(f);
  unsigned r = (u + 0x7FFFu + ((u >> 16) & 1u)) >> 16;
  return (short)r;
}
// hot-path packing: round-half-up, pair-packed in pure C (no asm — round-5 lesson)
static __device__ __forceinline__ bf16x4 mk4_bf16(float a, float b, float c, float d) {
  unsigned p0 = ((__float_as_uint(a) + 0x8000u) >> 16) | ((__float_as_uint(b) + 0x8000u) & 0xFFFF0000u);
  unsigned p1 = ((__float_as_uint(c) + 0x8000u) >> 16) | ((__float_as_uint(d) + 0x8000u) & 0xFFFF0000u);
  bf16x4 r;
  r[0] = (short)(p0 & 0xFFFFu); r[1] = (short)(p0 >> 16);
  r[2] = (short)(p1 & 0xFFFFu); r[3] = (short)(p1 >> 16);
  return r;
}
// gelu via exp2 with folded 1/ln2 (1.5957691 * 1.4426950 = 2.3023442)
static __device__ __forceinline__ float gelu_tanh(float u) {
  float u2 = u * u;
  float t  = fmaf(0.044715f, u2, 1.0f);
  float z2 = u * t * 2.3023441539623485f;
  float e  = __builtin_amdgcn_exp2f(-z2);
  return u / (1.0f + e);
}

// ---------------------------------------------------------------------------
// Kernel P: dynamic position bias table (465 x 4) via tiny MLP
// ---------------------------------------------------------------------------
static __device__ __forceinline__ void ln4_relu(float* p, const float* g, const float* b) {
  float mu = 0.25f * (p[0] + p[1] + p[2] + p[3]);
  float d0 = p[0] - mu, d1 = p[1] - mu, d2 = p[2] - mu, d3 = p[3] - mu;
  float var = 0.25f * (d0 * d0 + d1 * d1 + d2 * d2 + d3 * d3);
  float rs = rsqrtf(var + 1e-5f);
  p[0] = fmaxf(d0 * rs * g[0] + b[0], 0.0f);
  p[1] = fmaxf(d1 * rs * g[1] + b[1], 0.0f);
  p[2] = fmaxf(d2 * rs * g[2] + b[2], 0.0f);
  p[3] = fmaxf(d3 * rs * g[3] + b[3], 0.0f);
}
static __device__ __forceinline__ void mm4(const float* a, const float* w, const float* b, float* o) {
  #pragma unroll
  for (int j = 0; j < 4; ++j) {
    float s = b[j];
    #pragma unroll
    for (int i = 0; i < 4; ++i) s += a[i] * w[i * 4 + j];
    o[j] = s;
  }
}

__global__ void pbias_kernel(const float* __restrict__ pp_w, const float* __restrict__ pp_b,
                             const float* __restrict__ ln1g, const float* __restrict__ ln1b,
                             const float* __restrict__ l1w,  const float* __restrict__ l1b,
                             const float* __restrict__ ln2g, const float* __restrict__ ln2b,
                             const float* __restrict__ l2w,  const float* __restrict__ l2b,
                             const float* __restrict__ ln3g, const float* __restrict__ ln3b,
                             const float* __restrict__ l3w,  const float* __restrict__ l3b,
                             float* __restrict__ p_table) {
  int r = blockIdx.x * blockDim.x + threadIdx.x;
  if (r >= NBIA) return;
  float bh = (float)(r / 15 - 15);
  float bw = (float)(r % 15 - 7);
  float a[4], t[4];
  #pragma unroll
  for (int j = 0; j < 4; ++j) a[j] = bh * pp_w[j] + bw * pp_w[4 + j] + pp_b[j];
  ln4_relu(a, ln1g, ln1b);
  mm4(a, l1w, l1b, t);
  ln4_relu(t, ln2g, ln2b);
  mm4(t, l2w, l2b, a);
  ln4_relu(a, ln3g, ln3b);
  mm4(a, l3w, l3b, t);
  #pragma unroll
  for (int j = 0; j < 4; ++j) p_table[r * 4 + j] = t[j];
}

// ---------------------------------------------------------------------------
// bias_expand: p_table (465x4) -> dense bias_exp[h][q][k] f32, PRE-SCALED by
// 1/ln2 so the kernel's softmax is a single v_exp (exp2) per score.
// ---------------------------------------------------------------------------
__global__ void bias_expand_kernel(const float* __restrict__ p_table, float* __restrict__ bias_exp) {
  int gid = blockIdx.x * 256 + threadIdx.x;   // 16384 float4's
  int h   = gid >> 12;
  int rem = gid & 4095;
  int q   = rem >> 5;
  int k0  = (rem & 31) * 4;
  int qih = q >> 3, qiw = q & 7;
  float o[4];
  #pragma unroll
  for (int kk = 0; kk < 4; ++kk) {
    int k = k0 + kk;
    int ridx = (qih - (k >> 3) + 15) * 15 + (qiw - (k & 7) + 7);
    o[kk] = p_table[ridx * 4 + h] * INV_LN2;
  }
  f32x4 v = {o[0], o[1], o[2], o[3]};
  *(f32x4*)(bias_exp + gid * 4) = v;
}

// ---------------------------------------------------------------------------
// prep_w: weight frag images (q-scale * 1/ln2 folded)
// ---------------------------------------------------------------------------
__global__ void prep_w_kernel(const float* __restrict__ qkv_w, const float* __restrict__ proj_w,
                              short* __restrict__ wqkvF, short* __restrict__ projF) {
  int t = blockIdx.x * 256 + threadIdx.x;    // 16384
  if (t < 12288) {
    int slot = t >> 9, e = t & 511;
    int lp = e >> 3, j = e & 7;
    int ng = slot >> 1, s = slot & 1;
    int k   = 32 * s + 8 * (lp >> 4) + j;
    int col = 16 * ng + (lp & 15);
    float v = qkv_w[k * 192 + col];
    if (col < 64) v *= 0.25f * INV_LN2;
    wqkvF[t] = to_bf16(v);
  } else {
    int t2 = t - 12288;
    int slot = t2 >> 9, e = t2 & 511;
    int lp = e >> 3, j = e & 7;
    int ng = slot >> 1, s = slot & 1;
    int k   = 32 * s + 8 * (lp >> 4) + j;
    int col = 16 * ng + (lp & 15);
    projF[t2] = to_bf16(proj_w[k * 64 + col]);
  }
}

// ---------------------------------------------------------------------------
// prep_mlp_w (unchanged)
// ---------------------------------------------------------------------------
__global__ void prep_mlp_w_kernel(const float* __restrict__ fx1w, const float* __restrict__ fy1w,
                                  const float* __restrict__ fx2w, const float* __restrict__ fy2w,
                                  short* __restrict__ mlpW) {
  int gid = blockIdx.x * 256 + threadIdx.x;   // 65536
  int img = gid >> 14;
  int e   = gid & 16383;
  int slot = e >> 9, lp = (e >> 3) & 63, j = e & 7;
  float v;
  if (img < 2) {
    const float* w1 = img ? fy1w : fx1w;      // (64 x 256)
    int nt = slot >> 1, ks = slot & 1;
    int in_ch = ks * 32 + ((lp >> 4) << 3) + j;
    int hid   = nt * 16 + (lp & 15);
    v = w1[in_ch * HIDN + hid];
  } else {
    const float* w2 = (img & 1) ? fy2w : fx2w; // (256 x 64)
    int nt2 = slot >> 3, g2 = slot & 7;
    int hid = g2 * 32 + ((lp >> 4) << 3) + j;
    int oc  = nt2 * 16 + (lp & 15);
    v = w2[hid * CC + oc];
  }
  mlpW[gid] = to_bf16(v);
}

// ---------------------------------------------------------------------------
// Kernel FUSED (FINAL): attention (phases 1-4) + MLP (phase 5) with a 32 KB
// f32 LDS handoff (TOKF over dead QB/KB; MLP arenas over dead VT/PB).
// ---------------------------------------------------------------------------

#define ATT_LOADB(biasreg, qt) { \
  _Pragma("unroll") \
  for (int kt_ = 0; kt_ < 8; ++kt_) \
    biasreg[kt_] = *(const f32x4*)(biasH + (16 * (qt) + l15) * 128 + 16 * kt_ + 4 * lg); }

#define ATT_LOADQ(qfreg, qt) { \
  qfreg = (bf16x8){0, 0, 0, 0, 0, 0, 0, 0}; \
  if (l < 32) { \
    int row_ = 16 * (qt) + l15; \
    qfreg = *(const bf16x8*)(QB_ + ((row_ * 128 + h * 32 + lg * 16) ^ ((row_ & 7) << 4))); } }

#define ATT_BODY(qt, biasreg, qfreg) { \
  f32x4 s_[8]; \
  _Pragma("unroll") \
  for (int kt_ = 0; kt_ < 8; ++kt_) \
    s_[kt_] = __builtin_amdgcn_mfma_f32_16x16x32_bf16(kf[kt_], qfreg, biasreg[kt_], 0, 0, 0); \
  float sum_ = 0.0f; \
  _Pragma("unroll") \
  for (int kt_ = 0; kt_ < 8; ++kt_) { \
    s_[kt_][0] = __builtin_amdgcn_exp2f(s_[kt_][0]); \
    s_[kt_][1] = __builtin_amdgcn_exp2f(s_[kt_][1]); \
    s_[kt_][2] = __builtin_amdgcn_exp2f(s_[kt_][2]); \
    s_[kt_][3] = __builtin_amdgcn_exp2f(s_[kt_][3]); \
    sum_ += (s_[kt_][0] + s_[kt_][1]) + (s_[kt_][2] + s_[kt_][3]); } \
  sum_ += __shfl_xor(sum_, 16); \
  sum_ += __shfl_xor(sum_, 32); \
  float inv_ = 1.0f / sum_; \
  _Pragma("unroll") \
  for (int kt_ = 0; kt_ < 8; ++kt_) { \
    int k0_ = 16 * kt_ + 4 * lg; \
    *(bf16x4*)(PBw + ((l15 * 256 + k0_ * 2) ^ pswz)) = mk4_bf16(s_[kt_][0], s_[kt_][1], s_[kt_][2], s_[kt_][3]); } \
  f32x4 pacc_ = {0.0f, 0.0f, 0.0f, 0.0f}; \
  _Pragma("unroll") \
  for (int ks_ = 0; ks_ < 4; ++ks_) { \
    bf16x8 pa_ = *(const bf16x8*)(PBw + ((l15 * 256 + ks_ * 64 + lg * 16) ^ pswz)); \
    pacc_ = __builtin_amdgcn_mfma_f32_16x16x32_bf16(vf[ks_], pa_, pacc_, 0, 0, 0); } \
  pacc_[0] *= inv_; pacc_[1] *= inv_; pacc_[2] *= inv_; pacc_[3] *= inv_; \
  *(bf16x4*)(TOK_ + (((16 * (qt) + l15) * 128 + (h * 16 + lg * 4) * 2) ^ (((16 * (qt) + l15) & 7) << 4))) \
      = mk4_bf16(pacc_[0], pacc_[1], pacc_[2], pacc_[3]); }

__launch_bounds__(256, 2)
__global__ void fused_kernel(const float* __restrict__ x, const float* __restrict__ y,
                             const float* __restrict__ n1g, const float* __restrict__ n1b,
                             const float* __restrict__ qkv_b, const float* __restrict__ proj_b,
                             const float* __restrict__ bias_exp,
                             const short* __restrict__ wqkvF, const short* __restrict__ projF,
                             const float* __restrict__ n2g, const float* __restrict__ n2b,
                             const float* __restrict__ fx1b, const float* __restrict__ fx2b,
                             const float* __restrict__ fy1b, const float* __restrict__ fy2b,
                             const short* __restrict__ mlpW,
                             float* __restrict__ out) {
  __shared__ __align__(16) char smem[81920];
  char* const TOK_  = smem;            // 16 KB [128 tok][64 ch] bf16 (LN'd; later attn-out)
  char* const QB_   = smem + 16384;    // 16 KB (phases 2-3)
  char* const KB_   = smem + 32768;    // 16 KB (phases 2-3)
  char* const VT_   = smem + 49152;    // 16 KB (phases 2-3)
  char* const PB_   = smem + 65536;    // 16 KB (phase 3)
  char* const TOKF_ = smem + 16384;    // 32 KB f32 [128 tok][64 ch] (phase 4-5, over QB/KB)
  char* const MAR_  = smem + 49152;    // 32 KB MLP arenas (phase 5, over VT/PB)

  const int tid = threadIdx.x;
  const int l   = tid & 63;
  const int l15 = l & 15;
  const int lg  = l >> 4;
  const int wv  = __builtin_amdgcn_readfirstlane(tid >> 6);

  const int widx = blockIdx.x;
  const int b  = widx >> 10;
  const int wl = widx & 1023;
  const int wh = wl >> 5, ww = wl & 31;

  // ---- phase 1: gather + LN(norm1) -> bf16 token tile (row-swizzled) ----
  {
    const int lane16 = tid & 15;
    const float4 g4 = *(const float4*)(n1g + lane16 * 4);
    const float4 b4 = *(const float4*)(n1b + lane16 * 4);
    #pragma unroll
    for (int ps = 0; ps < 8; ++ps) {
      int t  = ps * 16 + (tid >> 4);
      int g  = t & 63;
      const float* src = ((t & 64) ? y : x)
          + ((long long)b * LL + (long long)(wh * GG + (g >> 3)) * W0c + (ww * GG + (g & 7))) * CC
          + lane16 * 4;
      float4 v = *(const float4*)src;
      float s  = v.x + v.y + v.z + v.w;
      float s2 = v.x * v.x + v.y * v.y + v.z * v.z + v.w * v.w;
      #pragma unroll
      for (int m = 1; m < 16; m <<= 1) { s += __shfl_xor(s, m); s2 += __shfl_xor(s2, m); }
      float mu  = s * (1.0f / 64.0f);
      float var = fmaxf(s2 * (1.0f / 64.0f) - mu * mu, 0.0f);
      float rs  = rsqrtf(var + 1e-5f);
      bf16x4 w4 = mk4_bf16((v.x - mu) * rs * g4.x + b4.x,
                           (v.y - mu) * rs * g4.y + b4.y,
                           (v.z - mu) * rs * g4.z + b4.z,
                           (v.w - mu) * rs * g4.w + b4.w);
      *(bf16x4*)(TOK_ + ((t * 128 + lane16 * 8) ^ ((t & 7) << 4))) = w4;
    }
  }
  __syncthreads();

  // ---- phase 2: QKV (waves 0,1 -> Q^T; waves 2,3 -> K^T; all -> one V tile) ----
  {
    bf16x8 awq[2][2];
    #pragma unroll
    for (int ct = 0; ct < 2; ++ct)
      #pragma unroll
      for (int ks = 0; ks < 2; ++ks)
        awq[ct][ks] = *(const bf16x8*)((const char*)wqkvF + ((((2 * wv + ct) * 2 + ks)) << 10) + l * 16);
    bf16x8 bwv[2];
    #pragma unroll
    for (int ks = 0; ks < 2; ++ks)
      bwv[ks] = *(const bf16x8*)((const char*)wqkvF + (((8 + wv) * 2 + ks) << 10) + l * 16);

    f32x4 bq[2];
    #pragma unroll
    for (int ct = 0; ct < 2; ++ct) {
      f32x4 bb = *(const f32x4*)(qkv_b + (2 * wv + ct) * 16 + lg * 4);
      if (wv < 2) {
        const float qs = 0.25f * INV_LN2;
        bb[0] *= qs; bb[1] *= qs; bb[2] *= qs; bb[3] *= qs;
      }
      bq[ct] = bb;
    }
    const float bv = qkv_b[128 + wv * 16 + l15];
    char* const QKbuf = (wv < 2) ? QB_ : KB_;
    const int chv = wv * 16 + l15;
    const int vswz = (chv & 7) << 4;

    #pragma unroll
    for (int nt = 0; nt < 8; ++nt) {
      const int row = 16 * nt + l15;
      const int rswz = (row & 7) << 4;
      bf16x8 t0 = *(const bf16x8*)(TOK_ + ((row * 128 +  0 + lg * 16) ^ rswz));
      bf16x8 t1 = *(const bf16x8*)(TOK_ + ((row * 128 + 64 + lg * 16) ^ rswz));
      #pragma unroll
      for (int ct = 0; ct < 2; ++ct) {
        f32x4 a = bq[ct];
        a = __builtin_amdgcn_mfma_f32_16x16x32_bf16(awq[ct][0], t0, a, 0, 0, 0);
        a = __builtin_amdgcn_mfma_f32_16x16x32_bf16(awq[ct][1], t1, a, 0, 0, 0);
        int chL = (((2 * wv + ct) * 16) & 63) + lg * 4;
        *(bf16x4*)(QKbuf + ((row * 128 + chL * 2) ^ rswz)) = mk4_bf16(a[0], a[1], a[2], a[3]);
      }
      {
        f32x4 a = {bv, bv, bv, bv};
        a = __builtin_amdgcn_mfma_f32_16x16x32_bf16(t0, bwv[0], a, 0, 0, 0);
        a = __builtin_amdgcn_mfma_f32_16x16x32_bf16(t1, bwv[1], a, 0, 0, 0);
        int tok0 = 16 * nt + lg * 4;
        *(bf16x4*)(VT_ + ((chv * 256 + tok0 * 2) ^ vswz)) = mk4_bf16(a[0], a[1], a[2], a[3]);
      }
    }
  }
  __syncthreads();

  // ---- phase 3: attention, wave = head.  S^T = K x Q (swapped). ----
  {
    const int h = wv;
    const float* biasH = bias_exp + h * 16384;
    bf16x8 kf[8];
    #pragma unroll
    for (int kt = 0; kt < 8; ++kt) {
      bf16x8 f = {0, 0, 0, 0, 0, 0, 0, 0};
      if (l < 32) {
        int row = 16 * kt + l15;
        f = *(const bf16x8*)(KB_ + ((row * 128 + h * 32 + lg * 16) ^ ((row & 7) << 4)));
      }
      kf[kt] = f;
    }
    bf16x8 vf[4];
    #pragma unroll
    for (int ks = 0; ks < 4; ++ks) {
      int row = h * 16 + l15;
      vf[ks] = *(const bf16x8*)(VT_ + ((row * 256 + ks * 64 + lg * 16) ^ ((row & 7) << 4)));
    }
    char* const PBw = PB_ + wv * 4096;
    const int pswz = (l15 & 7) << 4;

    f32x4 biasE[8], biasO[8];
    bf16x8 qfE, qfO;
    ATT_LOADB(biasE, 0);
    ATT_LOADQ(qfE, 0);
    #pragma unroll
    for (int qq = 0; qq < 4; ++qq) {
      ATT_LOADB(biasO, 2 * qq + 1);
      ATT_LOADQ(qfO, 2 * qq + 1);
      ATT_BODY(2 * qq, biasE, qfE);
      if (qq < 3) {
        ATT_LOADB(biasE, 2 * qq + 2);
        ATT_LOADQ(qfE, 2 * qq + 2);
      }
      ATT_BODY(2 * qq + 1, biasO, qfO);
    }
  }
  __syncthreads();   // attn-out complete in TOK_; QB/KB/VT/PB now dead

  // ---- phase 4: proj^T + residual -> TOKF (f32, LDS) ----
  {
    bf16x8 pa2[2];
    #pragma unroll
    for (int ks = 0; ks < 2; ++ks)
      pa2[ks] = *(const bf16x8*)((const char*)projF + (((wv * 2 + ks)) << 10) + l * 16);
    const f32x4 bp = *(const f32x4*)(proj_b + wv * 16 + lg * 4);
    #pragma unroll
    for (int nt = 0; nt < 8; ++nt) {
      const int row = 16 * nt + l15;       // token
      const int rswz = (row & 7) << 4;
      bf16x8 t0 = *(const bf16x8*)(TOK_ + ((row * 128 +  0 + lg * 16) ^ rswz));
      bf16x8 t1 = *(const bf16x8*)(TOK_ + ((row * 128 + 64 + lg * 16) ^ rswz));
      f32x4 acc = bp;
      acc = __builtin_amdgcn_mfma_f32_16x16x32_bf16(pa2[0], t0, acc, 0, 0, 0);
      acc = __builtin_amdgcn_mfma_f32_16x16x32_bf16(pa2[1], t1, acc, 0, 0, 0);
      int g = row & 63;
      long long base = ((long long)b * LL + (long long)(wh * GG + (g >> 3)) * W0c + (ww * GG + (g & 7))) * CC
                       + wv * 16 + lg * 4;
      const float* src = ((row & 64) ? y : x) + base;
      f32x4 sv = *(const f32x4*)src;
      sv[0] += acc[0]; sv[1] += acc[1]; sv[2] += acc[2]; sv[3] += acc[3];
      *(f32x4*)(TOKF_ + row * 256 + (((wv * 64 + lg * 16)) ^ rswz)) = sv;
    }
  }
  __syncthreads();   // TOKF complete (all channels from all waves)

  // ---- phase 5: fused MLP.  Wave wv owns tokens [32wv, 32wv+32); modality
  //      mod = wv>=2.  Exact mlp_mfma pipeline, LN input from TOKF. ----
  {
    const int mod = wv >> 1;
    const float* b1 = mod ? fy1b : fx1b;
    const float* b2 = mod ? fy2b : fx2b;
    const short* w1T = mlpW + mod * 16384;
    const short* w2T = mlpW + 32768 + mod * 16384;
    char* const TOKw = MAR_ + wv * 8192;       // 32 rows, stride 144 B
    char* const HBw  = TOKw + 4608;            // 32 rows, stride 80 B

    {
      const f32x4 g4 = *(const f32x4*)(n2g + l15 * 4);
      const f32x4 b4 = *(const f32x4*)(n2b + l15 * 4);
      #pragma unroll
      for (int ps = 0; ps < 8; ++ps) {
        int t   = ps * 4 + lg;                 // local 0..31
        int row = wv * 32 + t;                 // window token
        f32x4 v = *(const f32x4*)(TOKF_ + row * 256 + ((l15 * 16) ^ ((row & 7) << 4)));
        float s  = v[0] + v[1] + v[2] + v[3];
        float s2 = v[0] * v[0] + v[1] * v[1] + v[2] * v[2] + v[3] * v[3];
        #pragma unroll
        for (int m = 1; m < 16; m <<= 1) { s += __shfl_xor(s, m); s2 += __shfl_xor(s2, m); }
        float mu  = s * (1.0f / 64.0f);
        float var = fmaxf(s2 * (1.0f / 64.0f) - mu * mu, 0.0f);
        float rs  = rsqrtf(var + 1e-5f);
        bf16x4 w4 = mk4_bf16((v[0] - mu) * rs * g4[0] + b4[0],
                             (v[1] - mu) * rs * g4[1] + b4[1],
                             (v[2] - mu) * rs * g4[2] + b4[2],
                             (v[3] - mu) * rs * g4[3] + b4[3]);
        *(bf16x4*)(TOKw + t * 144 + l15 * 8) = w4;
      }
    }

    bf16x8 tokB[2][2];
    #pragma unroll
    for (int ct = 0; ct < 2; ++ct)
      #pragma unroll
      for (int ks = 0; ks < 2; ++ks)
        tokB[ct][ks] = *(const bf16x8*)(TOKw + (16 * ct + l15) * 144 + ks * 64 + lg * 16);

    f32x4 acc2[4][2];
    #pragma unroll
    for (int n = 0; n < 4; ++n) {
      f32x4 bb = *(const f32x4*)(b2 + n * 16 + lg * 4);
      acc2[n][0] = bb; acc2[n][1] = bb;
    }

    #pragma unroll 1
    for (int g2 = 0; g2 < 8; ++g2) {
      #pragma unroll
      for (int sub = 0; sub < 2; ++sub) {
        const int nt = g2 * 2 + sub;
        bf16x8 wa0 = *(const bf16x8*)(w1T + ((nt * 2 + 0) << 9) + l * 8);
        bf16x8 wa1 = *(const bf16x8*)(w1T + ((nt * 2 + 1) << 9) + l * 8);
        f32x4 z = {0.0f, 0.0f, 0.0f, 0.0f};
        f32x4 d0 = __builtin_amdgcn_mfma_f32_16x16x32_bf16(wa0, tokB[0][0], z, 0, 0, 0);
        d0 = __builtin_amdgcn_mfma_f32_16x16x32_bf16(wa1, tokB[0][1], d0, 0, 0, 0);
        f32x4 d1 = __builtin_amdgcn_mfma_f32_16x16x32_bf16(wa0, tokB[1][0], z, 0, 0, 0);
        d1 = __builtin_amdgcn_mfma_f32_16x16x32_bf16(wa1, tokB[1][1], d1, 0, 0, 0);
        f32x4 b1v = *(const f32x4*)(b1 + nt * 16 + lg * 4);
        bf16x4 h0 = mk4_bf16(gelu_tanh(d0[0] + b1v[0]), gelu_tanh(d0[1] + b1v[1]),
                             gelu_tanh(d0[2] + b1v[2]), gelu_tanh(d0[3] + b1v[3]));
        bf16x4 h1 = mk4_bf16(gelu_tanh(d1[0] + b1v[0]), gelu_tanh(d1[1] + b1v[1]),
                             gelu_tanh(d1[2] + b1v[2]), gelu_tanh(d1[3] + b1v[3]));
        *(bf16x4*)(HBw + l15 * 80        + sub * 32 + lg * 8) = h0;
        *(bf16x4*)(HBw + (16 + l15) * 80 + sub * 32 + lg * 8) = h1;
      }
      bf16x8 hb0 = *(const bf16x8*)(HBw + l15 * 80        + lg * 16);
      bf16x8 hb1 = *(const bf16x8*)(HBw + (16 + l15) * 80 + lg * 16);
      #pragma unroll
      for (int n = 0; n < 4; ++n) {
        bf16x8 wa = *(const bf16x8*)(w2T + ((n * 8 + g2) << 9) + l * 8);
        acc2[n][0] = __builtin_amdgcn_mfma_f32_16x16x32_bf16(wa, hb0, acc2[n][0], 0, 0, 0);
        acc2[n][1] = __builtin_amdgcn_mfma_f32_16x16x32_bf16(wa, hb1, acc2[n][1], 0, 0, 0);
      }
    }

    // epilogue: resid (TOKF) + mlp_out -> final store
    #pragma unroll
    for (int n = 0; n < 4; ++n)
      #pragma unroll
      for (int ct = 0; ct < 2; ++ct) {
        int row = wv * 32 + 16 * ct + l15;     // window token
        int ch  = n * 16 + lg * 4;
        f32x4 r = *(const f32x4*)(TOKF_ + row * 256 + ((ch * 4) ^ ((row & 7) << 4)));
        r[0] += acc2[n][ct][0]; r[1] += acc2[n][ct][1];
        r[2] += acc2[n][ct][2]; r[3] += acc2[n][ct][3];
        int g = row & 63;
        long long base = ((long long)b * LL + (long long)(wh * GG + (g >> 3)) * W0c + (ww * GG + (g & 7))) * CC + ch;
        float* dst = out + ((row & 64) ? MODSZ : 0) + base;
        *(f32x4*)dst = r;
      }
  }
}

// ---------------------------------------------------------------------------
extern "C" void kernel_launch(void* const* d_in, const int* in_sizes, int n_in,
                              void* d_out, int out_size, void* d_ws, size_t ws_size,
                              hipStream_t stream) {
  const float* x      = (const float*)d_in[0];
  const float* y      = (const float*)d_in[1];
  const float* n1g    = (const float*)d_in[2];
  const float* n1b    = (const float*)d_in[3];
  const float* qkv_w  = (const float*)d_in[4];
  const float* qkv_b  = (const float*)d_in[5];
  const float* proj_w = (const float*)d_in[6];
  const float* proj_b = (const float*)d_in[7];
  const float* pp_w   = (const float*)d_in[8];
  const float* pp_b   = (const float*)d_in[9];
  const float* ln1g   = (const float*)d_in[10];
  const float* ln1b   = (const float*)d_in[11];
  const float* l1w    = (const float*)d_in[12];
  const float* l1b    = (const float*)d_in[13];
  const float* ln2g   = (const float*)d_in[14];
  const float* ln2b   = (const float*)d_in[15];
  const float* l2w    = (const float*)d_in[16];
  const float* l2b    = (const float*)d_in[17];
  const float* ln3g   = (const float*)d_in[18];
  const float* ln3b   = (const float*)d_in[19];
  const float* l3w    = (const float*)d_in[20];
  const float* l3b    = (const float*)d_in[21];
  const float* n2g    = (const float*)d_in[22];
  const float* n2b    = (const float*)d_in[23];
  const float* fx1w   = (const float*)d_in[24];
  const float* fx1b   = (const float*)d_in[25];
  const float* fx2w   = (const float*)d_in[26];
  const float* fx2b   = (const float*)d_in[27];
  const float* fy1w   = (const float*)d_in[28];
  const float* fy1b   = (const float*)d_in[29];
  const float* fy2w   = (const float*)d_in[30];
  const float* fy2b   = (const float*)d_in[31];
  (void)in_sizes; (void)n_in; (void)out_size; (void)ws_size;

  float* out = (float*)d_out;
  char*  ws  = (char*)d_ws;
  float* p_table  = (float*)(ws + WS_PTAB);
  float* bias_exp = (float*)(ws + WS_BIAS);
  short* wqkvF    = (short*)(ws + WS_WQKV);
  short* projF    = (short*)(ws + WS_WPROJ);
  short* mlpW     = (short*)(ws + WS_MLPW);

  pbias_kernel<<<1, 512, 0, stream>>>(pp_w, pp_b, ln1g, ln1b, l1w, l1b,
                                      ln2g, ln2b, l2w, l2b, ln3g, ln3b, l3w, l3b, p_table);
  bias_expand_kernel<<<64, 256, 0, stream>>>(p_table, bias_exp);
  prep_w_kernel<<<64, 256, 0, stream>>>(qkv_w, proj_w, wqkvF, projF);
  prep_mlp_w_kernel<<<256, 256, 0, stream>>>(fx1w, fy1w, fx2w, fy2w, mlpW);
  fused_kernel<<<NWIN, 256, 0, stream>>>(x, y, n1g, n1b, qkv_b, proj_b,
                                         bias_exp, wqkvF, projF,
                                         n2g, n2b, fx1b, fx2b, fy1b, fy2b, mlpW, out);
}